// Round 13
// baseline (465.570 us; speedup 1.0000x reference)
//
#include <hip/hip_runtime.h>

#define NN 16384
#define NE 131072
#define HH 128

typedef unsigned short u16;
typedef unsigned int u32;
typedef __attribute__((ext_vector_type(8))) short short8;
typedef __attribute__((ext_vector_type(4))) float f32x4;
typedef __attribute__((ext_vector_type(2))) float f32x2;
typedef __attribute__((ext_vector_type(2))) u32 u32x2;
typedef u16 __attribute__((may_alias)) u16a;
typedef u32 __attribute__((may_alias)) u32a;
typedef short8 __attribute__((may_alias)) short8a;
typedef u32x2 __attribute__((may_alias)) u32x2a;

#define CFENCE() asm volatile("" ::: "memory")

__device__ __forceinline__ float b2f(u16 u){ u32 i=((u32)u)<<16; float f; __builtin_memcpy(&f,&i,4); return f; }
__device__ __forceinline__ u16 f2b(float f){ u32 i; __builtin_memcpy(&i,&f,4); u32 r=(i+0x7fffu+((i>>16)&1u))>>16; return (u16)r; }
__device__ __forceinline__ float blo(u32 v){ return b2f((u16)(v&0xffffu)); }
__device__ __forceinline__ float bhi(u32 v){ return b2f((u16)(v>>16)); }
__device__ __forceinline__ u32 pk(float a, float b){ return (u32)f2b(a) | ((u32)f2b(b)<<16); }
__device__ __forceinline__ float siluf(float x){ return x/(1.f+__expf(-x)); }

// LDS XOR swizzle for 256B-row tiles
#define SW8(b) ((b) ^ ((((b)>>8)&7)<<4))
__device__ __forceinline__ u32 ldsr32(const char* base, int b){ return *(const u32a*)(base + SW8(b)); }
__device__ __forceinline__ void ldsw16(char* base, int b, u16 v){ *(u16a*)(base + SW8(b)) = v; }
__device__ __forceinline__ short8 ldsr128(const char* base, int b){ return *(const short8a*)(base + SW8(b)); }
__device__ __forceinline__ void ldsw64(char* base, int b, u32x2 v){ *(u32x2a*)(base + SW8(b)) = v; }

// ws byte layout:
//   0          : xacc f32 [N,128] (8MB)
//   8388608    : vacc f32 [3N,128] (25MB) -> end 33,554,432
//   33554432   : Y [3N,256] bf16 (25MB)
//   58720256   : xn [N,128] bf16 (4MB)
//   67108864   : vec3 [3N,128] bf16 (12.6MB)
//   79691776   : qkv [N,384] bf16 (12.6MB)
//   92274688   : v12 [3N,256] bf16 (25MB) -> 117,440,512
//   117440512  : params bf16 (~545KB)
//   117985280  : cnt int[16384]; 118050816 cur; 118116352 se int[E]
#define PBASE 58720256u   // u16 units = byte 117,440,512
enum : unsigned {
  O_Wq=PBASE+0, O_Wk=PBASE+16384, O_Wv=PBASE+32768, O_Wdk=PBASE+49152,
  O_Wdv=PBASE+65536, O_Wf=PBASE+81920, O_Wwsrc=PBASE+98304, O_Wwtrg=PBASE+114688,
  O_Wvec=PBASE+131072, O_Ws=PBASE+180224, O_Wo=PBASE+212992, O_Wagg=PBASE+262144,
  O_bq=PBASE+270336, O_bk=PBASE+270464, O_bv=PBASE+270592, O_bdk=PBASE+270720,
  O_bdv=PBASE+270848, O_bs=PBASE+270976, O_bo=PBASE+271232, O_bf=PBASE+271616,
  O_lng=PBASE+271744, O_lnb=PBASE+271872, O_agg=PBASE+272000
};
#define CNT_OFF 117985280u
#define CUR_OFF 118050816u
#define SE_OFF  118116352u

struct Seg { const float* s; u32 off; u32 n; };
struct Pack { Seg d[25]; int cnt; };

// ---------------- f32 -> bf16 conversion (params only) ----------------
__global__ __launch_bounds__(256) void k_cvt(Pack p, u16* __restrict__ base){
  int tid = blockIdx.x*blockDim.x + threadIdx.x;
  int stride = gridDim.x*blockDim.x;
  for (int s=0; s<p.cnt; ++s){
    const float* src = p.d[s].s;
    u16* dst = base + p.d[s].off;
    int n = (int)p.d[s].n, n4 = n>>2;
    const f32x4* s4 = (const f32x4*)src;
    for (int i=tid; i<n4; i+=stride){
      f32x4 v = s4[i];
      u32x2 o; o[0] = pk(v[0], v[1]); o[1] = pk(v[2], v[3]);
      *(u32x2a*)(dst + 4*(size_t)i) = o;
    }
    for (int i = n4*4 + tid; i < n; i += stride) dst[i] = f2b(src[i]);
  }
}

// ---------------- edge sort by dst: histogram, scan, place ----------------
__global__ __launch_bounds__(256) void k_hist(const int* __restrict__ ei, int* __restrict__ cnt){
  int e = blockIdx.x*256 + threadIdx.x;
  atomicAdd(&cnt[ei[NE + e]], 1);
}
__global__ __launch_bounds__(1024) void k_scan(const int* __restrict__ cnt, int* __restrict__ cur){
  __shared__ int part[1024];
  int t = threadIdx.x;
  int base = t*16;
  int local[16]; int s = 0;
#pragma unroll
  for (int k=0;k<16;++k){ local[k] = cnt[base+k]; s += local[k]; }
  part[t] = s;
  __syncthreads();
  for (int d=1; d<1024; d<<=1){
    int v = (t>=d) ? part[t-d] : 0;
    __syncthreads();
    part[t] += v;
    __syncthreads();
  }
  int run = (t>0) ? part[t-1] : 0;
#pragma unroll
  for (int k=0;k<16;++k){ cur[base+k] = run; run += local[k]; }
}
__global__ __launch_bounds__(256) void k_place(const int* __restrict__ ei, int* __restrict__ cur,
                                               int* __restrict__ se){
  int e = blockIdx.x*256 + threadIdx.x;
  int p = atomicAdd(&cur[ei[NE + e]], 1);
  se[p] = e;
}

// one 16x16 output tile helper (A/W bf16 row-major)
template<int NK>
__device__ __forceinline__ f32x4 mm16(const u16* A, int lda, const u16* W, int ldw, f32x4 acc){
  int lane = threadIdx.x & 63;
  const u16* pa = A + (lane & 15)*lda + ((lane>>4)<<3);
  const u16* pw = W + (lane & 15)*ldw + ((lane>>4)<<3);
#pragma unroll
  for (int kc = 0; kc < NK; ++kc){
    short8 a = *(const short8a*)(pa + kc*32);
    short8 b = *(const short8a*)(pw + kc*32);
    acc = __builtin_amdgcn_mfma_f32_16x16x32_bf16(a, b, acc, 0, 0, 0);
  }
  return acc;
}

// ---------------- LayerNorm (f32 in -> bf16 out) ----------------
__global__ __launch_bounds__(256) void k_ln(const float* __restrict__ x, const u16* __restrict__ pb,
                                            u16* __restrict__ xn){
  int wid = threadIdx.x>>6, lane = threadIdx.x & 63;
  int n = blockIdx.x*4 + wid;
  f32x2 v = *(const f32x2*)(x + (size_t)n*HH + 2*lane);
  float a0 = v[0], a1 = v[1];
  float s = a0 + a1;
#pragma unroll
  for (int m=32; m; m>>=1) s += __shfl_xor(s, m);
  float mu = s*(1.f/128.f);
  float d0 = a0-mu, d1 = a1-mu;
  float vs = d0*d0 + d1*d1;
#pragma unroll
  for (int m=32; m; m>>=1) vs += __shfl_xor(vs, m);
  float rs = rsqrtf(vs*(1.f/128.f) + 1e-5f);
  u32 gg = *(const u32a*)(pb + O_lng + 2*lane);
  u32 bb = *(const u32a*)(pb + O_lnb + 2*lane);
  *(u32a*)(xn + (size_t)n*HH + 2*lane) = pk(d0*rs*blo(gg)+blo(bb), d1*rs*bhi(gg)+bhi(bb));
}

// ---------------- qkv = xn @ [Wq|Wk|Wv]^T + b ----------------
__global__ __launch_bounds__(256) void k_gemm_qkv(const u16* __restrict__ xn,
    const u16* __restrict__ pb, u16* __restrict__ qkv){
  int wid = threadIdx.x>>6, lane = threadIdx.x & 63;
  int ct = blockIdx.y*4 + wid;          // 0..23
  int r0 = blockIdx.x*16;
  unsigned wo, bo_;
  if (ct < 8)      { wo = O_Wq; bo_ = O_bq; }
  else if (ct <16) { wo = O_Wk; bo_ = O_bk; }
  else             { wo = O_Wv; bo_ = O_bv; }
  int c0 = (ct & 7)*16;
  f32x4 acc = {0,0,0,0};
  acc = mm16<4>(xn + (size_t)r0*HH, HH, pb + wo + c0*HH, HH, acc);
  int col = ct*16 + (lane & 15);
  float bb = b2f(pb[bo_ + c0 + (lane&15)]);
#pragma unroll
  for (int j=0;j<4;++j){
    int r = r0 + ((lane>>4)<<2) + j;
    qkv[(size_t)r*384 + col] = f2b(acc[j] + bb);
  }
}

// ---------------- vec GEMMs: stage 16 rows of vec (f32->bf16 LDS), all 40 col-tiles ----------------
__global__ __launch_bounds__(256) void k_gemm_vec(const float* __restrict__ vecf,
    const u16* __restrict__ pb,
    u16* __restrict__ v12, u16* __restrict__ vec3, u16* __restrict__ Y){
  __shared__ u16 At[16*128];
  int tid = threadIdx.x, wid = tid>>6, lane = tid & 63;
  int r0 = blockIdx.x*16;               // rows in [3N]
  {
    const float* src = vecf + (size_t)r0*HH;
    for (int i = tid*4; i < 2048; i += 1024){
      f32x4 v = *(const f32x4*)(src + i);
      u32x2 o; o[0] = pk(v[0], v[1]); o[1] = pk(v[2], v[3]);
      *(u32x2a*)(At + i) = o;
    }
  }
  __syncthreads();
  for (int ct = wid; ct < 40; ct += 4){
    unsigned wo; int wc0;
    if (ct < 24)      { wo = O_Wvec;  wc0 = ct*16; }
    else if (ct < 32) { wo = O_Wwsrc; wc0 = (ct-24)*16; }
    else              { wo = O_Wwtrg; wc0 = (ct-32)*16; }
    f32x4 acc = {0,0,0,0};
    acc = mm16<4>(At, HH, pb + wo + wc0*HH, HH, acc);
    u16* dst; int ldc, dc0;
    if (ct < 16)      { dst = v12;  ldc = 256; dc0 = ct*16; }           // vec1|vec2
    else if (ct < 24) { dst = vec3; ldc = 128; dc0 = (ct-16)*16; }      // vec3
    else if (ct < 32) { dst = Y;    ldc = 256; dc0 = (ct-24)*16; }      // Ysrc
    else              { dst = Y;    ldc = 256; dc0 = (ct-32)*16 + 128; }// Ytrg
    int col = dc0 + (lane & 15);
#pragma unroll
    for (int j=0;j<4;++j){
      int r = r0 + ((lane>>4)<<2) + j;
      dst[(size_t)r*ldc + col] = f2b(acc[j]);
    }
  }
}

// ---------------- FUSED edge kernel: 32KB LDS, zero barriers, fenced phases ----------------
// fsA: f_ij -> silu(ff) -> vmsg                    (16KB)
// fsB: dk -> dv -> ex0 -> ex1 -> s1 -> s2          (16KB)
__global__ __launch_bounds__(256) void k_edge(const float* __restrict__ f_ij,
    const u16* __restrict__ pb,
    const u16* __restrict__ qkv, const u16* __restrict__ Y,
    const int* __restrict__ ei, const int* __restrict__ se,
    const float* __restrict__ r_ij, const float* __restrict__ d_ij,
    const float* __restrict__ vecf, const float* __restrict__ aggf,
    float* __restrict__ df, float* __restrict__ xacc, float* __restrict__ vacc){
  __shared__ u16 fsA[64*128];
  __shared__ u16 fsB[64*128];
  char* fsb = (char*)fsA;
  char* bsb = (char*)fsB;
  int tid = threadIdx.x, wid = tid>>6, lane = tid & 63;
  int t0 = blockIdx.x*64;
  int ereg=0, dreg=0, sreg=0;
  if (lane < 16){
    ereg = se[t0 + wid*16 + lane];
    dreg = ei[NE + ereg];
    sreg = ei[ereg];
  }
  int h0 = 2*lane;
  // ---- stage this wave's 16 sorted f_ij rows into fsA (swizzled) ----
#pragma unroll
  for (int pass=0; pass<8; ++pass){
    int idx = pass*256 + lane*4;
    int rloc = idx >> 7, col = idx & 127;
    int er = __shfl(ereg, rloc);
    f32x4 v = *(const f32x4*)(f_ij + (size_t)er*HH + col);
    u32x2 o; o[0]=pk(v[0],v[1]); o[1]=pk(v[2],v[3]);
    ldsw64(fsb, (wid*16 + rloc)*256 + col*2, o);
  }
  CFENCE();
  // ---- A fragments of f_ij (registers; live through dv GEMM) ----
  int ab = (wid*16 + (lane&15))*256 + ((lane>>4)<<4);
  short8 a0 = ldsr128(fsb, ab);
  short8 a1 = ldsr128(fsb, ab + 64);
  short8 a2 = ldsr128(fsb, ab + 128);
  short8 a3 = ldsr128(fsb, ab + 192);
  CFENCE();
  // ---- ff GEMM -> overwrite fsA with silu(ff) (per-tile immediate) ----
#pragma unroll
  for (int cf=0; cf<8; ++cf){
    const u16* pw = pb + O_Wf + (size_t)(cf*16 + (lane&15))*HH + ((lane>>4)<<3);
    f32x4 acc = {0,0,0,0};
    acc = __builtin_amdgcn_mfma_f32_16x16x32_bf16(a0, *(const short8a*)(pw),      acc, 0,0,0);
    acc = __builtin_amdgcn_mfma_f32_16x16x32_bf16(a1, *(const short8a*)(pw + 32), acc, 0,0,0);
    acc = __builtin_amdgcn_mfma_f32_16x16x32_bf16(a2, *(const short8a*)(pw + 64), acc, 0,0,0);
    acc = __builtin_amdgcn_mfma_f32_16x16x32_bf16(a3, *(const short8a*)(pw + 96), acc, 0,0,0);
    float bb = b2f(pb[O_bf + cf*16 + (lane&15)]);
#pragma unroll
    for (int j=0;j<4;++j){
      int r = wid*16 + ((lane>>4)<<2) + j;
      ldsw16(fsb, r*256 + (cf*16 + (lane&15))*2, f2b(siluf(acc[j] + bb)));
    }
  }
  CFENCE();
  // ---- dk GEMM -> fsB ----
#pragma unroll
  for (int ct=0; ct<8; ++ct){
    const u16* pw = pb + O_Wdk + (size_t)(ct*16 + (lane&15))*HH + ((lane>>4)<<3);
    f32x4 acc = {0,0,0,0};
    acc = __builtin_amdgcn_mfma_f32_16x16x32_bf16(a0, *(const short8a*)(pw),      acc, 0,0,0);
    acc = __builtin_amdgcn_mfma_f32_16x16x32_bf16(a1, *(const short8a*)(pw + 32), acc, 0,0,0);
    acc = __builtin_amdgcn_mfma_f32_16x16x32_bf16(a2, *(const short8a*)(pw + 64), acc, 0,0,0);
    acc = __builtin_amdgcn_mfma_f32_16x16x32_bf16(a3, *(const short8a*)(pw + 96), acc, 0,0,0);
    float bb = b2f(pb[O_bdk + ct*16 + (lane&15)]);
#pragma unroll
    for (int j=0;j<4;++j){
      int r = wid*16 + ((lane>>4)<<2) + j;
      ldsw16(bsb, r*256 + (ct*16 + (lane&15))*2, f2b(siluf(acc[j] + bb)));
    }
  }
  CFENCE();
  // ---- pass1: attn (dk) + df (ff); cache attn + vv in regs ----
  float attn_r[16];
  u32 vvr[16];
  {
    int pdst = -1; u32 qq=0, ya0=0, ya1=0, ya2=0;
#pragma unroll
    for (int i=0;i<16;++i){
      int el = wid*16 + i;
      int e   = __shfl(ereg, i);
      int dst = __shfl(dreg, i);
      int src = __shfl(sreg, i);
      if (dst != pdst){
        qq  = *(const u32a*)(qkv + (size_t)dst*384 + h0);
        ya0 = *(const u32a*)(Y + ((size_t)dst*3+0)*256 + 128 + h0);
        ya1 = *(const u32a*)(Y + ((size_t)dst*3+1)*256 + 128 + h0);
        ya2 = *(const u32a*)(Y + ((size_t)dst*3+2)*256 + 128 + h0);
        pdst = dst;
      }
      u32 kk  = *(const u32a*)(qkv + (size_t)src*384 + 128 + h0);
      u32 vv  = *(const u32a*)(qkv + (size_t)src*384 + 256 + h0);
      u32 yb0 = *(const u32a*)(Y + ((size_t)src*3+0)*256 + h0);
      u32 yb1 = *(const u32a*)(Y + ((size_t)src*3+1)*256 + h0);
      u32 yb2 = *(const u32a*)(Y + ((size_t)src*3+2)*256 + h0);
      float r   = r_ij[e];
      float dc0 = d_ij[(size_t)e*3+0];
      float dc1 = d_ij[(size_t)e*3+1];
      float dc2 = d_ij[(size_t)e*3+2];
      u32 dk = ldsr32(bsb, el*256 + h0*2);
      u32 ff = ldsr32(fsb, el*256 + h0*2);
      float p = blo(qq)*blo(kk)*blo(dk) + bhi(qq)*bhi(kk)*bhi(dk);
      p += __shfl_xor(p,1); p += __shfl_xor(p,2); p += __shfl_xor(p,4);
      float cut = 0.5f*(__cosf(0.6283185307f*r)+1.f) * (r < 5.f ? 1.f : 0.f);
      attn_r[i] = siluf(p)*cut;
      vvr[i] = vv;
      float ab0,ab1, ad0,ad1, bd0,bd1, ss;
      ab0 = blo(ya0)*blo(yb0); ab1 = bhi(ya0)*bhi(yb0);
      ad0 = blo(ya0)*dc0;      ad1 = bhi(ya0)*dc0;
      bd0 = blo(yb0)*dc0;      bd1 = bhi(yb0)*dc0;
      ss  = dc0*dc0;
      ab0 += blo(ya1)*blo(yb1); ab1 += bhi(ya1)*bhi(yb1);
      ad0 += blo(ya1)*dc1;      ad1 += bhi(ya1)*dc1;
      bd0 += blo(yb1)*dc1;      bd1 += bhi(yb1)*dc1;
      ss  += dc1*dc1;
      ab0 += blo(ya2)*blo(yb2); ab1 += bhi(ya2)*bhi(yb2);
      ad0 += blo(ya2)*dc2;      ad1 += bhi(ya2)*dc2;
      bd0 += blo(yb2)*dc2;      bd1 += bhi(yb2)*dc2;
      ss  += dc2*dc2;
      float t = 2.f - ss;
      f32x2 dfo; dfo[0] = blo(ff)*(ab0 - ad0*bd0*t); dfo[1] = bhi(ff)*(ab1 - ad1*bd1*t);
      *(f32x2*)(df + (size_t)e*HH + h0) = dfo;
    }
  }
  CFENCE();
  // ---- dv GEMM -> fsB (dk dead) ----
#pragma unroll
  for (int ct=0; ct<8; ++ct){
    const u16* pw = pb + O_Wdv + (size_t)(ct*16 + (lane&15))*HH + ((lane>>4)<<3);
    f32x4 acc = {0,0,0,0};
    acc = __builtin_amdgcn_mfma_f32_16x16x32_bf16(a0, *(const short8a*)(pw),      acc, 0,0,0);
    acc = __builtin_amdgcn_mfma_f32_16x16x32_bf16(a1, *(const short8a*)(pw + 32), acc, 0,0,0);
    acc = __builtin_amdgcn_mfma_f32_16x16x32_bf16(a2, *(const short8a*)(pw + 64), acc, 0,0,0);
    acc = __builtin_amdgcn_mfma_f32_16x16x32_bf16(a3, *(const short8a*)(pw + 96), acc, 0,0,0);
    float bb = b2f(pb[O_bdv + ct*16 + (lane&15)]);
#pragma unroll
    for (int j=0;j<4;++j){
      int r = wid*16 + ((lane>>4)<<2) + j;
      ldsw16(bsb, r*256 + (ct*16 + (lane&15))*2, f2b(siluf(acc[j] + bb)));
    }
  }
  CFENCE();
  // ---- pass2: vmsg = vv*dv*attn -> fsA (ff dead) ----
#pragma unroll
  for (int i=0;i<16;++i){
    int el = wid*16 + i;
    u32 dv = ldsr32(bsb, el*256 + h0*2);
    float m0 = blo(vvr[i])*blo(dv)*attn_r[i];
    float m1 = bhi(vvr[i])*bhi(dv)*attn_r[i];
    *(u32a*)(fsb + SW8(el*256 + h0*2)) = pk(m0, m1);
  }
  CFENCE();
  float absA = fabsf(aggf[0]);
  // ---- vmsg fragments (reused for ex + s GEMMs) ----
  short8 sa0 = ldsr128(fsb, ab);
  short8 sa1 = ldsr128(fsb, ab + 64);
  short8 sa2 = ldsr128(fsb, ab + 128);
  short8 sa3 = ldsr128(fsb, ab + 192);
  CFENCE();
  // ---- C1a: ex0 (k = vmsg[0:64]) -> fsB ----
#pragma unroll
  for (int ct=0; ct<8; ++ct){
    const u16* pw = pb + O_Wagg + (size_t)(ct*16 + (lane&15))*64 + ((lane>>4)<<3);
    f32x4 acc = {0,0,0,0};
    acc = __builtin_amdgcn_mfma_f32_16x16x32_bf16(sa0, *(const short8a*)(pw),      acc, 0,0,0);
    acc = __builtin_amdgcn_mfma_f32_16x16x32_bf16(sa1, *(const short8a*)(pw + 32), acc, 0,0,0);
#pragma unroll
    for (int j=0;j<4;++j){
      int r = wid*16 + ((lane>>4)<<2) + j;
      ldsw16(bsb, r*256 + (ct*16 + (lane&15))*2, f2b(fminf(fmaxf(acc[j],0.f),1.f)));
    }
  }
  CFENCE();
  // ---- scatter-xA: vmsg + absA*ml*ex0 (run-merged) ----
  {
    int rdst = -1; float xc0=0.f, xc1=0.f;
#pragma unroll
    for (int i=0;i<16;++i){
      int el = wid*16 + i;
      int dst = __shfl(dreg, i);
      if (dst != rdst){
        if (rdst >= 0){
          atomicAdd(&xacc[(size_t)rdst*HH + h0],     xc0);
          atomicAdd(&xacc[(size_t)rdst*HH + h0 + 1], xc1);
        }
        rdst = dst; xc0 = xc1 = 0.f;
      }
      u32 mm  = ldsr32(fsb, el*256 + h0*2);
      u32 ml  = ldsr32(fsb, el*256 + (h0&63)*2);
      u32 ex0 = ldsr32(bsb, el*256 + h0*2);
      xc0 += blo(mm) + absA*blo(ml)*blo(ex0);
      xc1 += bhi(mm) + absA*bhi(ml)*bhi(ex0);
    }
    if (rdst >= 0){
      atomicAdd(&xacc[(size_t)rdst*HH + h0],     xc0);
      atomicAdd(&xacc[(size_t)rdst*HH + h0 + 1], xc1);
    }
  }
  CFENCE();
  // ---- C1b: ex1 (k = vmsg[64:128]) -> fsB ----
#pragma unroll
  for (int ct=0; ct<8; ++ct){
    const u16* pw = pb + O_Wagg + (size_t)(ct*16 + (lane&15))*64 + ((lane>>4)<<3);
    f32x4 acc = {0,0,0,0};
    acc = __builtin_amdgcn_mfma_f32_16x16x32_bf16(sa2, *(const short8a*)(pw),      acc, 0,0,0);
    acc = __builtin_amdgcn_mfma_f32_16x16x32_bf16(sa3, *(const short8a*)(pw + 32), acc, 0,0,0);
#pragma unroll
    for (int j=0;j<4;++j){
      int r = wid*16 + ((lane>>4)<<2) + j;
      ldsw16(bsb, r*256 + (ct*16 + (lane&15))*2, f2b(fminf(fmaxf(acc[j],0.f),1.f)));
    }
  }
  CFENCE();
  // ---- scatter-xB: absA*mh*ex1 (run-merged) ----
  {
    int rdst = -1; float xc0=0.f, xc1=0.f;
#pragma unroll
    for (int i=0;i<16;++i){
      int el = wid*16 + i;
      int dst = __shfl(dreg, i);
      if (dst != rdst){
        if (rdst >= 0){
          atomicAdd(&xacc[(size_t)rdst*HH + h0],     xc0);
          atomicAdd(&xacc[(size_t)rdst*HH + h0 + 1], xc1);
        }
        rdst = dst; xc0 = xc1 = 0.f;
      }
      u32 mh  = ldsr32(fsb, el*256 + 128 + (h0&63)*2);
      u32 ex1 = ldsr32(bsb, el*256 + h0*2);
      xc0 += absA*blo(mh)*blo(ex1);
      xc1 += absA*bhi(mh)*bhi(ex1);
    }
    if (rdst >= 0){
      atomicAdd(&xacc[(size_t)rdst*HH + h0],     xc0);
      atomicAdd(&xacc[(size_t)rdst*HH + h0 + 1], xc1);
    }
  }
  CFENCE();
  // ---- C2a: s1 GEMM -> fsB ----
#pragma unroll
  for (int ct=0; ct<8; ++ct){
    const u16* pw = pb + O_Ws + (size_t)(ct*16 + (lane&15))*HH + ((lane>>4)<<3);
    f32x4 acc = {0,0,0,0};
    acc = __builtin_amdgcn_mfma_f32_16x16x32_bf16(sa0, *(const short8a*)(pw),      acc, 0,0,0);
    acc = __builtin_amdgcn_mfma_f32_16x16x32_bf16(sa1, *(const short8a*)(pw + 32), acc, 0,0,0);
    acc = __builtin_amdgcn_mfma_f32_16x16x32_bf16(sa2, *(const short8a*)(pw + 64), acc, 0,0,0);
    acc = __builtin_amdgcn_mfma_f32_16x16x32_bf16(sa3, *(const short8a*)(pw + 96), acc, 0,0,0);
    float bb = b2f(pb[O_bs + ct*16 + (lane&15)]);
#pragma unroll
    for (int j=0;j<4;++j){
      int r = wid*16 + ((lane>>4)<<2) + j;
      ldsw16(bsb, r*256 + (ct*16 + (lane&15))*2, f2b(siluf(acc[j] + bb)));
    }
  }
  CFENCE();
  // ---- scatter-v1: vec[src]*s1 (run-merged) ----
  {
    int rdst = -1;
    float vc00=0.f,vc01=0.f, vc10=0.f,vc11=0.f, vc20=0.f,vc21=0.f;
#pragma unroll
    for (int i=0;i<16;++i){
      int el = wid*16 + i;
      int dst = __shfl(dreg, i);
      int src = __shfl(sreg, i);
      if (dst != rdst){
        if (rdst >= 0){
          atomicAdd(&vacc[((size_t)rdst*3+0)*HH + h0],     vc00);
          atomicAdd(&vacc[((size_t)rdst*3+0)*HH + h0 + 1], vc01);
          atomicAdd(&vacc[((size_t)rdst*3+1)*HH + h0],     vc10);
          atomicAdd(&vacc[((size_t)rdst*3+1)*HH + h0 + 1], vc11);
          atomicAdd(&vacc[((size_t)rdst*3+2)*HH + h0],     vc20);
          atomicAdd(&vacc[((size_t)rdst*3+2)*HH + h0 + 1], vc21);
        }
        rdst = dst;
        vc00=vc01=vc10=vc11=vc20=vc21=0.f;
      }
      u32 s1 = ldsr32(bsb, el*256 + h0*2);
      f32x2 vv0 = *(const f32x2*)(vecf + ((size_t)src*3+0)*HH + h0);
      f32x2 vv1 = *(const f32x2*)(vecf + ((size_t)src*3+1)*HH + h0);
      f32x2 vv2 = *(const f32x2*)(vecf + ((size_t)src*3+2)*HH + h0);
      vc00 += vv0[0]*blo(s1);  vc01 += vv0[1]*bhi(s1);
      vc10 += vv1[0]*blo(s1);  vc11 += vv1[1]*bhi(s1);
      vc20 += vv2[0]*blo(s1);  vc21 += vv2[1]*bhi(s1);
    }
    if (rdst >= 0){
      atomicAdd(&vacc[((size_t)rdst*3+0)*HH + h0],     vc00);
      atomicAdd(&vacc[((size_t)rdst*3+0)*HH + h0 + 1], vc01);
      atomicAdd(&vacc[((size_t)rdst*3+1)*HH + h0],     vc10);
      atomicAdd(&vacc[((size_t)rdst*3+1)*HH + h0 + 1], vc11);
      atomicAdd(&vacc[((size_t)rdst*3+2)*HH + h0],     vc20);
      atomicAdd(&vacc[((size_t)rdst*3+2)*HH + h0 + 1], vc21);
    }
  }
  CFENCE();
  // ---- C2b: s2 GEMM -> fsB ----
#pragma unroll
  for (int ct=0; ct<8; ++ct){
    const u16* pw = pb + O_Ws + (size_t)(128 + ct*16 + (lane&15))*HH + ((lane>>4)<<3);
    f32x4 acc = {0,0,0,0};
    acc = __builtin_amdgcn_mfma_f32_16x16x32_bf16(sa0, *(const short8a*)(pw),      acc, 0,0,0);
    acc = __builtin_amdgcn_mfma_f32_16x16x32_bf16(sa1, *(const short8a*)(pw + 32), acc, 0,0,0);
    acc = __builtin_amdgcn_mfma_f32_16x16x32_bf16(sa2, *(const short8a*)(pw + 64), acc, 0,0,0);
    acc = __builtin_amdgcn_mfma_f32_16x16x32_bf16(sa3, *(const short8a*)(pw + 96), acc, 0,0,0);
    float bb = b2f(pb[O_bs + 128 + ct*16 + (lane&15)]);
#pragma unroll
    for (int j=0;j<4;++j){
      int r = wid*16 + ((lane>>4)<<2) + j;
      ldsw16(bsb, r*256 + (ct*16 + (lane&15))*2, f2b(siluf(acc[j] + bb)));
    }
  }
  CFENCE();
  // ---- scatter-v2: s2*d (run-merged) ----
  {
    int rdst = -1;
    float vc00=0.f,vc01=0.f, vc10=0.f,vc11=0.f, vc20=0.f,vc21=0.f;
#pragma unroll
    for (int i=0;i<16;++i){
      int el = wid*16 + i;
      int e   = __shfl(ereg, i);
      int dst = __shfl(dreg, i);
      if (dst != rdst){
        if (rdst >= 0){
          atomicAdd(&vacc[((size_t)rdst*3+0)*HH + h0],     vc00);
          atomicAdd(&vacc[((size_t)rdst*3+0)*HH + h0 + 1], vc01);
          atomicAdd(&vacc[((size_t)rdst*3+1)*HH + h0],     vc10);
          atomicAdd(&vacc[((size_t)rdst*3+1)*HH + h0 + 1], vc11);
          atomicAdd(&vacc[((size_t)rdst*3+2)*HH + h0],     vc20);
          atomicAdd(&vacc[((size_t)rdst*3+2)*HH + h0 + 1], vc21);
        }
        rdst = dst;
        vc00=vc01=vc10=vc11=vc20=vc21=0.f;
      }
      u32 s2 = ldsr32(bsb, el*256 + h0*2);
      float dc0 = d_ij[(size_t)e*3+0];
      float dc1 = d_ij[(size_t)e*3+1];
      float dc2 = d_ij[(size_t)e*3+2];
      vc00 += blo(s2)*dc0;  vc01 += bhi(s2)*dc0;
      vc10 += blo(s2)*dc1;  vc11 += bhi(s2)*dc1;
      vc20 += blo(s2)*dc2;  vc21 += bhi(s2)*dc2;
    }
    if (rdst >= 0){
      atomicAdd(&vacc[((size_t)rdst*3+0)*HH + h0],     vc00);
      atomicAdd(&vacc[((size_t)rdst*3+0)*HH + h0 + 1], vc01);
      atomicAdd(&vacc[((size_t)rdst*3+1)*HH + h0],     vc10);
      atomicAdd(&vacc[((size_t)rdst*3+1)*HH + h0 + 1], vc11);
      atomicAdd(&vacc[((size_t)rdst*3+2)*HH + h0],     vc20);
      atomicAdd(&vacc[((size_t)rdst*3+2)*HH + h0 + 1], vc21);
    }
  }
}

// ---------------- update: o = x_agg @ Wo^T + bo (MFMA); vec_dot inline; f32 out ----------------
__global__ __launch_bounds__(256) void k_update(const float* __restrict__ xacc,
    const u16* __restrict__ pb, const u16* __restrict__ v12, const u16* __restrict__ vec3,
    const float* __restrict__ vacc,
    float* __restrict__ dx, float* __restrict__ dvec){
  int wid = threadIdx.x>>6, lane = threadIdx.x & 63;
  int ct = blockIdx.y*4 + wid;   // 0..7
  int r0 = blockIdx.x*16;
  int c0 = ct*16;
  f32x4 a1 = {0,0,0,0}, a2 = {0,0,0,0}, a3 = {0,0,0,0};
  const float* pa = xacc + (size_t)(r0 + (lane&15))*HH + ((lane>>4)<<3);
#pragma unroll
  for (int kc=0; kc<4; ++kc){
    f32x4 f0 = *(const f32x4*)(pa + kc*32);
    f32x4 f1 = *(const f32x4*)(pa + kc*32 + 4);
    short8 av;
    av[0]=(short)f2b(f0[0]); av[1]=(short)f2b(f0[1]); av[2]=(short)f2b(f0[2]); av[3]=(short)f2b(f0[3]);
    av[4]=(short)f2b(f1[0]); av[5]=(short)f2b(f1[1]); av[6]=(short)f2b(f1[2]); av[7]=(short)f2b(f1[3]);
    const u16* pw = pb + O_Wo + (size_t)(c0 + (lane&15))*HH + ((lane>>4)<<3) + kc*32;
    short8 b1 = *(const short8a*)(pw);
    short8 b2 = *(const short8a*)(pw + 128*HH);
    short8 b3 = *(const short8a*)(pw + 256*HH);
    a1 = __builtin_amdgcn_mfma_f32_16x16x32_bf16(av, b1, a1, 0,0,0);
    a2 = __builtin_amdgcn_mfma_f32_16x16x32_bf16(av, b2, a2, 0,0,0);
    a3 = __builtin_amdgcn_mfma_f32_16x16x32_bf16(av, b3, a3, 0,0,0);
  }
  int h = c0 + (lane & 15);
  float bo1 = b2f(pb[O_bo + h]), bo2 = b2f(pb[O_bo + 128 + h]), bo3 = b2f(pb[O_bo + 256 + h]);
#pragma unroll
  for (int j=0;j<4;++j){
    int r = r0 + ((lane>>4)<<2) + j;
    float o1 = a1[j]+bo1, o2 = a2[j]+bo2, o3 = a3[j]+bo3;
    float vdot = 0.f;
#pragma unroll
    for (int c=0;c<3;++c){
      const u16* row = v12 + ((size_t)r*3 + c)*256;
      vdot += b2f(row[h]) * b2f(row[128 + h]);
    }
    dx[(size_t)r*HH + h] = vdot*o2 + o3;
#pragma unroll
    for (int c=0;c<3;++c){
      size_t idx = ((size_t)r*3+c)*HH + h;
      dvec[idx] = b2f(vec3[idx])*o1 + vacc[idx];
    }
  }
}

extern "C" void kernel_launch(void* const* d_in, const int* in_sizes, int n_in,
                              void* d_out, int out_size, void* d_ws, size_t ws_size,
                              hipStream_t stream){
  (void)in_sizes; (void)n_in; (void)out_size; (void)ws_size;
  const float* x     = (const float*)d_in[0];
  const float* vecf  = (const float*)d_in[1];
  const int*   ei    = (const int*)d_in[2];
  const float* r_ij  = (const float*)d_in[3];
  const float* f_ij  = (const float*)d_in[4];
  const float* d_ij  = (const float*)d_in[5];
  const float* aggf  = (const float*)d_in[28];

  char* ws = (char*)d_ws;
  u16*   wsu   = (u16*)d_ws;
  float* xacc  = (float*)(ws + 0);          // [N,128] f32
  float* vacc  = (float*)(ws + 8388608);    // [3N,128] f32
  u16*   Ybuf  = (u16*)(ws + 33554432);     // [3N,256] bf16
  u16*   xn    = (u16*)(ws + 58720256);     // [N,128] bf16
  u16*   vec3  = (u16*)(ws + 67108864);     // [3N,128] bf16
  u16*   qkv   = (u16*)(ws + 79691776);     // [N,384] bf16
  u16*   v12   = (u16*)(ws + 92274688);     // [3N,256] bf16
  int*   cnt   = (int*)(ws + CNT_OFF);
  int*   cur   = (int*)(ws + CUR_OFF);
  int*   se    = (int*)(ws + SE_OFF);

  float* out  = (float*)d_out;
  float* dx   = out;
  float* dvec = out + (size_t)NN*128;
  float* df   = out + (size_t)NN*512;

  Pack p; int c = 0;
  auto add = [&](int idx, unsigned off, unsigned n){ p.d[c].s=(const float*)d_in[idx]; p.d[c].off=off; p.d[c].n=n; ++c; };
  add(8,  O_Wq,   16384); add(10, O_Wk,   16384); add(12, O_Wv,   16384);
  add(14, O_Wdk,  16384); add(16, O_Wdv,  16384); add(23, O_Wf,   16384);
  add(25, O_Wwsrc,16384); add(26, O_Wwtrg,16384);
  add(18, O_Wvec, 49152); add(19, O_Ws,   32768); add(21, O_Wo,   49152);
  add(27, O_Wagg,  8192);
  add(9,  O_bq, 128); add(11, O_bk, 128); add(13, O_bv, 128); add(15, O_bdk, 128);
  add(17, O_bdv, 128); add(20, O_bs, 256); add(22, O_bo, 384); add(24, O_bf, 128);
  add(6,  O_lng, 128); add(7,  O_lnb, 128); add(28, O_agg, 1);
  p.cnt = c;

  hipMemsetAsync(ws, 0, 33554432, stream);              // zero xacc+vacc
  hipMemsetAsync(ws + CNT_OFF, 0, 65536, stream);       // zero cnt
  k_hist<<<dim3(NE/256), 256, 0, stream>>>(ei, cnt);
  k_scan<<<dim3(1), 1024, 0, stream>>>(cnt, cur);
  k_place<<<dim3(NE/256), 256, 0, stream>>>(ei, cur, se);
  k_cvt<<<dim3(128), 256, 0, stream>>>(p, wsu);
  k_ln<<<dim3(NN/4), 256, 0, stream>>>(x, wsu, xn);
  k_gemm_qkv<<<dim3(NN/16, 6), 256, 0, stream>>>(xn, wsu, qkv);
  k_gemm_vec<<<dim3(3*NN/16), 256, 0, stream>>>(vecf, wsu, v12, vec3, Ybuf);
  k_edge<<<dim3(NE/64), 256, 0, stream>>>(f_ij, wsu, qkv, Ybuf, ei, se, r_ij, d_ij,
                                          vecf, aggf, df, xacc, vacc);
  k_update<<<dim3(NN/16, 2), 256, 0, stream>>>(xacc, wsu, v12, vec3, vacc, dx, dvec);
}

// Round 15
// 404.915 us; speedup vs baseline: 1.1498x; 1.1498x over previous
//
#include <hip/hip_runtime.h>

#define NN 16384
#define NE 131072
#define HH 128

typedef unsigned short u16;
typedef unsigned int u32;
typedef __attribute__((ext_vector_type(8))) short short8;
typedef __attribute__((ext_vector_type(4))) float f32x4;
typedef __attribute__((ext_vector_type(2))) float f32x2;
typedef __attribute__((ext_vector_type(2))) u32 u32x2;
typedef u16 __attribute__((may_alias)) u16a;
typedef u32 __attribute__((may_alias)) u32a;
typedef short8 __attribute__((may_alias)) short8a;
typedef u32x2 __attribute__((may_alias)) u32x2a;
typedef f32x4 __attribute__((may_alias)) f32x4a;

__device__ __forceinline__ float b2f(u16 u){ u32 i=((u32)u)<<16; float f; __builtin_memcpy(&f,&i,4); return f; }
__device__ __forceinline__ u16 f2b(float f){ u32 i; __builtin_memcpy(&i,&f,4); u32 r=(i+0x7fffu+((i>>16)&1u))>>16; return (u16)r; }
__device__ __forceinline__ float blo(u32 v){ return b2f((u16)(v&0xffffu)); }
__device__ __forceinline__ float bhi(u32 v){ return b2f((u16)(v>>16)); }
__device__ __forceinline__ u32 pk(float a, float b){ return (u32)f2b(a) | ((u32)f2b(b)<<16); }
__device__ __forceinline__ float siluf(float x){ return x/(1.f+__expf(-x)); }

// LDS XOR swizzles (row width 256B / 512B)
#define SW8(b) ((b) ^ ((((b)>>8)&7)<<4))
#define SW9(b) ((b) ^ ((((b)>>9)&7)<<4))
__device__ __forceinline__ u32 ldsr32(const char* base, int b){ return *(const u32a*)(base + SW8(b)); }
__device__ __forceinline__ void ldsw16(char* base, int b, u16 v){ *(u16a*)(base + SW8(b)) = v; }
__device__ __forceinline__ short8 ldsr128(const char* base, int b){ return *(const short8a*)(base + SW8(b)); }
__device__ __forceinline__ void ldsw64(char* base, int b, u32x2 v){ *(u32x2a*)(base + SW8(b)) = v; }

// ws byte layout:
//   0          : xacc f32 [N,128] (8MB)
//   8388608    : vacc f32 [3N,128] (25MB) -> end 33,554,432
//   33554432   : Y [3N,256] bf16 (25MB)
//   58720256   : xn [N,128] bf16 (4MB)
//   67108864   : vec3 [3N,128] bf16 (12.6MB)
//   79691776   : qkv [N,384] bf16 (12.6MB)
//   92274688   : v12 [3N,256] bf16 (25MB) -> 117,440,512
//   117440512  : params bf16 (~545KB)
//   117985280  : cnt int[16384]; 118050816 cur; 118116352 se int[E]
#define PBASE 58720256u   // u16 units = byte 117,440,512
enum : unsigned {
  O_Wq=PBASE+0, O_Wk=PBASE+16384, O_Wv=PBASE+32768, O_Wdk=PBASE+49152,
  O_Wdv=PBASE+65536, O_Wf=PBASE+81920, O_Wwsrc=PBASE+98304, O_Wwtrg=PBASE+114688,
  O_Wvec=PBASE+131072, O_Ws=PBASE+180224, O_Wo=PBASE+212992, O_Wagg=PBASE+262144,
  O_bq=PBASE+270336, O_bk=PBASE+270464, O_bv=PBASE+270592, O_bdk=PBASE+270720,
  O_bdv=PBASE+270848, O_bs=PBASE+270976, O_bo=PBASE+271232, O_bf=PBASE+271616,
  O_lng=PBASE+271744, O_lnb=PBASE+271872, O_agg=PBASE+272000
};
#define CNT_OFF 117985280u
#define CUR_OFF 118050816u
#define SE_OFF  118116352u

struct Seg { const float* s; u32 off; u32 n; };
struct Pack { Seg d[25]; int cnt; };

// ---------------- f32 -> bf16 conversion (params only) ----------------
__global__ __launch_bounds__(256) void k_cvt(Pack p, u16* __restrict__ base){
  int tid = blockIdx.x*blockDim.x + threadIdx.x;
  int stride = gridDim.x*blockDim.x;
  for (int s=0; s<p.cnt; ++s){
    const float* src = p.d[s].s;
    u16* dst = base + p.d[s].off;
    int n = (int)p.d[s].n, n4 = n>>2;
    const f32x4* s4 = (const f32x4*)src;
    for (int i=tid; i<n4; i+=stride){
      f32x4 v = s4[i];
      u32x2 o; o[0] = pk(v[0], v[1]); o[1] = pk(v[2], v[3]);
      *(u32x2a*)(dst + 4*(size_t)i) = o;
    }
    for (int i = n4*4 + tid; i < n; i += stride) dst[i] = f2b(src[i]);
  }
}

// ---------------- edge sort by dst: histogram, scan, place ----------------
__global__ __launch_bounds__(256) void k_hist(const int* __restrict__ ei, int* __restrict__ cnt){
  int e = blockIdx.x*256 + threadIdx.x;
  atomicAdd(&cnt[ei[NE + e]], 1);
}
__global__ __launch_bounds__(1024) void k_scan(const int* __restrict__ cnt, int* __restrict__ cur){
  __shared__ int part[1024];
  int t = threadIdx.x;
  int base = t*16;
  int local[16]; int s = 0;
#pragma unroll
  for (int k=0;k<16;++k){ local[k] = cnt[base+k]; s += local[k]; }
  part[t] = s;
  __syncthreads();
  for (int d=1; d<1024; d<<=1){
    int v = (t>=d) ? part[t-d] : 0;
    __syncthreads();
    part[t] += v;
    __syncthreads();
  }
  int run = (t>0) ? part[t-1] : 0;
#pragma unroll
  for (int k=0;k<16;++k){ cur[base+k] = run; run += local[k]; }
}
__global__ __launch_bounds__(256) void k_place(const int* __restrict__ ei, int* __restrict__ cur,
                                               int* __restrict__ se){
  int e = blockIdx.x*256 + threadIdx.x;
  int p = atomicAdd(&cur[ei[NE + e]], 1);
  se[p] = e;
}

// ---------------- LayerNorm (f32 in -> bf16 out) ----------------
__global__ __launch_bounds__(256) void k_ln(const float* __restrict__ x, const u16* __restrict__ pb,
                                            u16* __restrict__ xn){
  int wid = threadIdx.x>>6, lane = threadIdx.x & 63;
  int n = blockIdx.x*4 + wid;
  f32x2 v = *(const f32x2*)(x + (size_t)n*HH + 2*lane);
  float a0 = v[0], a1 = v[1];
  float s = a0 + a1;
#pragma unroll
  for (int m=32; m; m>>=1) s += __shfl_xor(s, m);
  float mu = s*(1.f/128.f);
  float d0 = a0-mu, d1 = a1-mu;
  float vs = d0*d0 + d1*d1;
#pragma unroll
  for (int m=32; m; m>>=1) vs += __shfl_xor(vs, m);
  float rs = rsqrtf(vs*(1.f/128.f) + 1e-5f);
  u32 gg = *(const u32a*)(pb + O_lng + 2*lane);
  u32 bb = *(const u32a*)(pb + O_lnb + 2*lane);
  *(u32a*)(xn + (size_t)n*HH + 2*lane) = pk(d0*rs*blo(gg)+blo(bb), d1*rs*bhi(gg)+bhi(bb));
}

// ---------------- qkv (64-row blocks, LDS-staged A, wave-per-coltile) ----------------
__global__ __launch_bounds__(256) void k_qkv64(const u16* __restrict__ xn,
    const u16* __restrict__ pb, u16* __restrict__ qkv){
  __shared__ u16 At[64*128];
  char* ab_ = (char*)At;
  int tid = threadIdx.x, wid = tid>>6, lane = tid & 63;
  int r0 = blockIdx.x*64;
#pragma unroll
  for (int pass=0; pass<4; ++pass){
    int idx = (pass*256 + tid)*8;            // u16 index, 8 u16 = 16B per iter
    int row = idx >> 7, col = idx & 127;
    f32x4 v = *(const f32x4a*)(xn + (size_t)(r0+row)*HH + col);   // 16B raw copy
    *(f32x4a*)(ab_ + SW8(row*256 + col*2)) = v;
  }
  __syncthreads();
  for (int ct = wid; ct < 24; ct += 4){
    unsigned wo, bo_;
    if (ct < 8)      { wo = O_Wq; bo_ = O_bq; }
    else if (ct <16) { wo = O_Wk; bo_ = O_bk; }
    else             { wo = O_Wv; bo_ = O_bv; }
    int c0 = (ct & 7)*16;
    const u16* pw = pb + wo + (size_t)(c0 + (lane&15))*HH + ((lane>>4)<<3);
    short8 w0 = *(const short8a*)(pw);
    short8 w1 = *(const short8a*)(pw + 32);
    short8 w2 = *(const short8a*)(pw + 64);
    short8 w3 = *(const short8a*)(pw + 96);
    float bb = b2f(pb[bo_ + c0 + (lane&15)]);
    int col = ct*16 + (lane & 15);
#pragma unroll
    for (int rg=0; rg<4; ++rg){
      int abse = (rg*16 + (lane&15))*256 + ((lane>>4)<<4);
      f32x4 acc = {0,0,0,0};
      acc = __builtin_amdgcn_mfma_f32_16x16x32_bf16(ldsr128(ab_, abse),       w0, acc, 0,0,0);
      acc = __builtin_amdgcn_mfma_f32_16x16x32_bf16(ldsr128(ab_, abse + 64),  w1, acc, 0,0,0);
      acc = __builtin_amdgcn_mfma_f32_16x16x32_bf16(ldsr128(ab_, abse + 128), w2, acc, 0,0,0);
      acc = __builtin_amdgcn_mfma_f32_16x16x32_bf16(ldsr128(ab_, abse + 192), w3, acc, 0,0,0);
#pragma unroll
      for (int j=0;j<4;++j){
        int r = r0 + rg*16 + ((lane>>4)<<2) + j;
        qkv[(size_t)r*384 + col] = f2b(acc[j] + bb);
      }
    }
  }
}

// ---------------- vec GEMMs (64-row blocks, LDS-staged f32->bf16 A) ----------------
__global__ __launch_bounds__(256) void k_vec64(const float* __restrict__ vecf,
    const u16* __restrict__ pb,
    u16* __restrict__ v12, u16* __restrict__ vec3, u16* __restrict__ Y){
  __shared__ u16 At[64*128];
  char* ab_ = (char*)At;
  int tid = threadIdx.x, wid = tid>>6, lane = tid & 63;
  int r0 = blockIdx.x*64;               // rows in [3N]
#pragma unroll
  for (int pass=0; pass<8; ++pass){
    int idx = pass*1024 + tid*4;         // f32 index
    int row = idx >> 7, col = idx & 127;
    f32x4 v = *(const f32x4*)(vecf + (size_t)(r0+row)*HH + col);
    u32x2 o; o[0]=pk(v[0],v[1]); o[1]=pk(v[2],v[3]);
    ldsw64(ab_, row*256 + col*2, o);
  }
  __syncthreads();
  for (int ct = wid; ct < 40; ct += 4){
    unsigned wo; int wc0;
    if (ct < 24)      { wo = O_Wvec;  wc0 = ct*16; }
    else if (ct < 32) { wo = O_Wwsrc; wc0 = (ct-24)*16; }
    else              { wo = O_Wwtrg; wc0 = (ct-32)*16; }
    const u16* pw = pb + wo + (size_t)(wc0 + (lane&15))*HH + ((lane>>4)<<3);
    short8 w0 = *(const short8a*)(pw);
    short8 w1 = *(const short8a*)(pw + 32);
    short8 w2 = *(const short8a*)(pw + 64);
    short8 w3 = *(const short8a*)(pw + 96);
    u16* dst; int ldc, dc0;
    if (ct < 16)      { dst = v12;  ldc = 256; dc0 = ct*16; }
    else if (ct < 24) { dst = vec3; ldc = 128; dc0 = (ct-16)*16; }
    else if (ct < 32) { dst = Y;    ldc = 256; dc0 = (ct-24)*16; }
    else              { dst = Y;    ldc = 256; dc0 = (ct-32)*16 + 128; }
    int col = dc0 + (lane & 15);
#pragma unroll
    for (int rg=0; rg<4; ++rg){
      int abse = (rg*16 + (lane&15))*256 + ((lane>>4)<<4);
      f32x4 acc = {0,0,0,0};
      acc = __builtin_amdgcn_mfma_f32_16x16x32_bf16(ldsr128(ab_, abse),       w0, acc, 0,0,0);
      acc = __builtin_amdgcn_mfma_f32_16x16x32_bf16(ldsr128(ab_, abse + 64),  w1, acc, 0,0,0);
      acc = __builtin_amdgcn_mfma_f32_16x16x32_bf16(ldsr128(ab_, abse + 128), w2, acc, 0,0,0);
      acc = __builtin_amdgcn_mfma_f32_16x16x32_bf16(ldsr128(ab_, abse + 192), w3, acc, 0,0,0);
#pragma unroll
      for (int j=0;j<4;++j){
        int r = r0 + rg*16 + ((lane>>4)<<2) + j;
        dst[(size_t)r*ldc + col] = f2b(acc[j]);
      }
    }
  }
}

// ---------------- FUSED edge kernel (round-11 proven version) ----------------
__global__ __launch_bounds__(256) void k_edge(const float* __restrict__ f_ij,
    const u16* __restrict__ pb,
    const u16* __restrict__ qkv, const u16* __restrict__ Y,
    const int* __restrict__ ei, const int* __restrict__ se,
    const float* __restrict__ r_ij, const float* __restrict__ d_ij,
    const float* __restrict__ vecf, const float* __restrict__ aggf,
    float* __restrict__ df, float* __restrict__ xacc, float* __restrict__ vacc){
  __shared__ u16 fs[64*128];
  __shared__ u16 g2s[64*256];
  char* fsb  = (char*)fs;
  char* g2b  = (char*)g2s;
  int tid = threadIdx.x, wid = tid>>6, lane = tid & 63;
  int t0 = blockIdx.x*64;
  int ereg=0, dreg=0, sreg=0;
  if (lane < 16){
    ereg = se[t0 + wid*16 + lane];
    dreg = ei[NE + ereg];
    sreg = ei[ereg];
  }
#pragma unroll
  for (int pass=0; pass<8; ++pass){
    int idx = pass*256 + lane*4;
    int rloc = idx >> 7, col = idx & 127;
    int er = __shfl(ereg, rloc);
    f32x4 v = *(const f32x4*)(f_ij + (size_t)er*HH + col);
    u32x2 o; o[0]=pk(v[0],v[1]); o[1]=pk(v[2],v[3]);
    int b = (wid*16 + rloc)*256 + col*2;
    *(u32x2a*)(fsb + SW8(b)) = o;
  }
  {
    int arow = wid*16 + (lane&15);
    int ab = arow*256 + ((lane>>4)<<4);
    short8 a0 = *(const short8a*)(fsb + SW8(ab));
    short8 a1 = *(const short8a*)(fsb + SW8(ab + 64));
    short8 a2 = *(const short8a*)(fsb + SW8(ab + 128));
    short8 a3 = *(const short8a*)(fsb + SW8(ab + 192));
    for (int ct=0; ct<16; ++ct){
      unsigned wo  = (ct<8) ? O_Wdk : O_Wdv;
      unsigned bo_ = (ct<8) ? O_bdk : O_bdv;
      int c0 = (ct&7)*16;
      const u16* pw = pb + wo + (size_t)(c0 + (lane&15))*HH + ((lane>>4)<<3);
      f32x4 acc = {0,0,0,0};
      acc = __builtin_amdgcn_mfma_f32_16x16x32_bf16(a0, *(const short8a*)(pw),      acc, 0,0,0);
      acc = __builtin_amdgcn_mfma_f32_16x16x32_bf16(a1, *(const short8a*)(pw + 32), acc, 0,0,0);
      acc = __builtin_amdgcn_mfma_f32_16x16x32_bf16(a2, *(const short8a*)(pw + 64), acc, 0,0,0);
      acc = __builtin_amdgcn_mfma_f32_16x16x32_bf16(a3, *(const short8a*)(pw + 96), acc, 0,0,0);
      float bb = b2f(pb[bo_ + c0 + (lane&15)]);
#pragma unroll
      for (int j=0;j<4;++j){
        int r = wid*16 + ((lane>>4)<<2) + j;
        int b = r*512 + (ct*16 + (lane&15))*2;
        *(u16a*)(g2b + SW9(b)) = f2b(siluf(acc[j] + bb));
      }
    }
    f32x4 ffa[8];
#pragma unroll
    for (int cf=0; cf<8; ++cf){
      const u16* pw = pb + O_Wf + (size_t)(cf*16 + (lane&15))*HH + ((lane>>4)<<3);
      f32x4 acc = {0,0,0,0};
      acc = __builtin_amdgcn_mfma_f32_16x16x32_bf16(a0, *(const short8a*)(pw),      acc, 0,0,0);
      acc = __builtin_amdgcn_mfma_f32_16x16x32_bf16(a1, *(const short8a*)(pw + 32), acc, 0,0,0);
      acc = __builtin_amdgcn_mfma_f32_16x16x32_bf16(a2, *(const short8a*)(pw + 64), acc, 0,0,0);
      acc = __builtin_amdgcn_mfma_f32_16x16x32_bf16(a3, *(const short8a*)(pw + 96), acc, 0,0,0);
      ffa[cf] = acc;
    }
#pragma unroll
    for (int cf=0; cf<8; ++cf){
      float bb = b2f(pb[O_bf + cf*16 + (lane&15)]);
#pragma unroll
      for (int j=0;j<4;++j){
        int r = wid*16 + ((lane>>4)<<2) + j;
        int b = r*256 + (cf*16 + (lane&15))*2;
        *(u16a*)(fsb + SW8(b)) = f2b(siluf(ffa[cf][j] + bb));
      }
    }
  }
  int h0 = 2*lane;
  {
    int pdst = -1; u32 qq=0, ya0=0, ya1=0, ya2=0;
    int e_c = __shfl(ereg, 0), src_c = __shfl(sreg, 0);
    u32 kk_c  = *(const u32a*)(qkv + (size_t)src_c*384 + 128 + h0);
    u32 vv_c  = *(const u32a*)(qkv + (size_t)src_c*384 + 256 + h0);
    u32 yb0_c = *(const u32a*)(Y + ((size_t)src_c*3+0)*256 + h0);
    u32 yb1_c = *(const u32a*)(Y + ((size_t)src_c*3+1)*256 + h0);
    u32 yb2_c = *(const u32a*)(Y + ((size_t)src_c*3+2)*256 + h0);
    float r_c   = r_ij[e_c];
    float dc0_c = d_ij[(size_t)e_c*3+0];
    float dc1_c = d_ij[(size_t)e_c*3+1];
    float dc2_c = d_ij[(size_t)e_c*3+2];
    for (int i=0;i<16;++i){
      int e = e_c;
      u32 kk=kk_c, vv=vv_c, yb0=yb0_c, yb1=yb1_c, yb2=yb2_c;
      float r=r_c, dc0=dc0_c, dc1=dc1_c, dc2=dc2_c;
      if (i<15){
        int e_n = __shfl(ereg, i+1), src_n = __shfl(sreg, i+1);
        kk_c  = *(const u32a*)(qkv + (size_t)src_n*384 + 128 + h0);
        vv_c  = *(const u32a*)(qkv + (size_t)src_n*384 + 256 + h0);
        yb0_c = *(const u32a*)(Y + ((size_t)src_n*3+0)*256 + h0);
        yb1_c = *(const u32a*)(Y + ((size_t)src_n*3+1)*256 + h0);
        yb2_c = *(const u32a*)(Y + ((size_t)src_n*3+2)*256 + h0);
        r_c   = r_ij[e_n];
        dc0_c = d_ij[(size_t)e_n*3+0];
        dc1_c = d_ij[(size_t)e_n*3+1];
        dc2_c = d_ij[(size_t)e_n*3+2];
        e_c = e_n;
      }
      int el = wid*16 + i;
      int dst = __shfl(dreg, i);
      if (dst != pdst){
        qq  = *(const u32a*)(qkv + (size_t)dst*384 + h0);
        ya0 = *(const u32a*)(Y + ((size_t)dst*3+0)*256 + 128 + h0);
        ya1 = *(const u32a*)(Y + ((size_t)dst*3+1)*256 + 128 + h0);
        ya2 = *(const u32a*)(Y + ((size_t)dst*3+2)*256 + 128 + h0);
        pdst = dst;
      }
      int bdk = el*512 + h0*2;
      u32 dk = *(const u32a*)(g2b + SW9(bdk));
      u32 dv = *(const u32a*)(g2b + SW9(bdk + 256));
      int bff = el*256 + h0*2;
      u32 ff = *(const u32a*)(fsb + SW8(bff));
      float p = blo(qq)*blo(kk)*blo(dk) + bhi(qq)*bhi(kk)*bhi(dk);
      p += __shfl_xor(p,1); p += __shfl_xor(p,2); p += __shfl_xor(p,4);
      float cut = 0.5f*(__cosf(0.6283185307f*r)+1.f) * (r < 5.f ? 1.f : 0.f);
      float attn = siluf(p)*cut;
      float m0 = blo(vv)*blo(dv)*attn, m1 = bhi(vv)*bhi(dv)*attn;
      float ab0,ab1, ad0,ad1, bd0,bd1, ss;
      ab0 = blo(ya0)*blo(yb0); ab1 = bhi(ya0)*bhi(yb0);
      ad0 = blo(ya0)*dc0;      ad1 = bhi(ya0)*dc0;
      bd0 = blo(yb0)*dc0;      bd1 = bhi(yb0)*dc0;
      ss  = dc0*dc0;
      ab0 += blo(ya1)*blo(yb1); ab1 += bhi(ya1)*bhi(yb1);
      ad0 += blo(ya1)*dc1;      ad1 += bhi(ya1)*dc1;
      bd0 += blo(yb1)*dc1;      bd1 += bhi(yb1)*dc1;
      ss  += dc1*dc1;
      ab0 += blo(ya2)*blo(yb2); ab1 += bhi(ya2)*bhi(yb2);
      ad0 += blo(ya2)*dc2;      ad1 += bhi(ya2)*dc2;
      bd0 += blo(yb2)*dc2;      bd1 += bhi(yb2)*dc2;
      ss  += dc2*dc2;
      float t = 2.f - ss;
      f32x2 dfo; dfo[0] = blo(ff)*(ab0 - ad0*bd0*t); dfo[1] = bhi(ff)*(ab1 - ad1*bd1*t);
      *(f32x2*)(df + (size_t)e*HH + h0) = dfo;
      *(u32a*)(fsb + SW8(bff)) = pk(m0, m1);
    }
  }
  float absA = fabsf(aggf[0]);
#pragma unroll
  for (int rr=0; rr<2; ++rr){
    int rt = wid*2 + rr;
    int el2 = wid*16 + 8*rr + ((lane&15)>>1);
    int pb2 = el2*256 + ((lane&15)&1)*128 + ((lane>>4)<<4);
    short8 b0 = *(const short8a*)(fsb + SW8(pb2));
    short8 b1 = *(const short8a*)(fsb + SW8(pb2 + 64));
    for (int ct=0; ct<8; ++ct){
      const u16* pw = pb + O_Wagg + (size_t)(ct*16 + (lane&15))*64 + ((lane>>4)<<3);
      f32x4 acc = {0,0,0,0};
      acc = __builtin_amdgcn_mfma_f32_16x16x32_bf16(b0, *(const short8a*)(pw),      acc, 0,0,0);
      acc = __builtin_amdgcn_mfma_f32_16x16x32_bf16(b1, *(const short8a*)(pw + 32), acc, 0,0,0);
#pragma unroll
      for (int j=0;j<4;++j){
        int r = rt*16 + ((lane>>4)<<2) + j;
        int b = r*256 + (ct*16 + (lane&15))*2;
        *(u16a*)(g2b + SW8(b)) = f2b(fminf(fmaxf(acc[j],0.f),1.f));
      }
    }
  }
  {
    int rdst = -1; float xc0=0.f, xc1=0.f;
    for (int i=0;i<16;++i){
      int el = wid*16 + i;
      int dst = __shfl(dreg, i);
      if (dst != rdst){
        if (rdst >= 0){
          atomicAdd(&xacc[(size_t)rdst*HH + h0],     xc0);
          atomicAdd(&xacc[(size_t)rdst*HH + h0 + 1], xc1);
        }
        rdst = dst; xc0 = xc1 = 0.f;
      }
      int bm = el*256;
      u32 mm = *(const u32a*)(fsb + SW8(bm + h0*2));
      u32 ml = *(const u32a*)(fsb + SW8(bm + (h0&63)*2));
      u32 mh = *(const u32a*)(fsb + SW8(bm + 128 + (h0&63)*2));
      u32 ex0 = *(const u32a*)(g2b + SW8((2*el)*256 + h0*2));
      u32 ex1 = *(const u32a*)(g2b + SW8((2*el+1)*256 + h0*2));
      xc0 += blo(mm) + absA*(blo(ml)*blo(ex0) + blo(mh)*blo(ex1));
      xc1 += bhi(mm) + absA*(bhi(ml)*bhi(ex0) + bhi(mh)*bhi(ex1));
    }
    if (rdst >= 0){
      atomicAdd(&xacc[(size_t)rdst*HH + h0],     xc0);
      atomicAdd(&xacc[(size_t)rdst*HH + h0 + 1], xc1);
    }
  }
  {
    int arow = wid*16 + (lane&15);
    int ab = arow*256 + ((lane>>4)<<4);
    short8 sa0 = *(const short8a*)(fsb + SW8(ab));
    short8 sa1 = *(const short8a*)(fsb + SW8(ab + 64));
    short8 sa2 = *(const short8a*)(fsb + SW8(ab + 128));
    short8 sa3 = *(const short8a*)(fsb + SW8(ab + 192));
    for (int ct=0; ct<16; ++ct){
      const u16* pw = pb + O_Ws + (size_t)(ct*16 + (lane&15))*HH + ((lane>>4)<<3);
      f32x4 acc = {0,0,0,0};
      acc = __builtin_amdgcn_mfma_f32_16x16x32_bf16(sa0, *(const short8a*)(pw),      acc, 0,0,0);
      acc = __builtin_amdgcn_mfma_f32_16x16x32_bf16(sa1, *(const short8a*)(pw + 32), acc, 0,0,0);
      acc = __builtin_amdgcn_mfma_f32_16x16x32_bf16(sa2, *(const short8a*)(pw + 64), acc, 0,0,0);
      acc = __builtin_amdgcn_mfma_f32_16x16x32_bf16(sa3, *(const short8a*)(pw + 96), acc, 0,0,0);
      float bb = b2f(pb[O_bs + ct*16 + (lane&15)]);
#pragma unroll
      for (int j=0;j<4;++j){
        int r = wid*16 + ((lane>>4)<<2) + j;
        int b = r*512 + (ct*16 + (lane&15))*2;
        *(u16a*)(g2b + SW9(b)) = f2b(siluf(acc[j] + bb));
      }
    }
  }
  {
    int rdst = -1;
    float vc00=0.f,vc01=0.f, vc10=0.f,vc11=0.f, vc20=0.f,vc21=0.f;
    int e_c = __shfl(ereg, 0), src_c = __shfl(sreg, 0);
    f32x2 v0_c = *(const f32x2*)(vecf + ((size_t)src_c*3+0)*HH + h0);
    f32x2 v1_c = *(const f32x2*)(vecf + ((size_t)src_c*3+1)*HH + h0);
    f32x2 v2_c = *(const f32x2*)(vecf + ((size_t)src_c*3+2)*HH + h0);
    float dc0_c = d_ij[(size_t)e_c*3+0];
    float dc1_c = d_ij[(size_t)e_c*3+1];
    float dc2_c = d_ij[(size_t)e_c*3+2];
    for (int i=0;i<16;++i){
      f32x2 vv0=v0_c, vv1=v1_c, vv2=v2_c;
      float dc0=dc0_c, dc1=dc1_c, dc2=dc2_c;
      if (i<15){
        int e_n = __shfl(ereg, i+1), src_n = __shfl(sreg, i+1);
        v0_c = *(const f32x2*)(vecf + ((size_t)src_n*3+0)*HH + h0);
        v1_c = *(const f32x2*)(vecf + ((size_t)src_n*3+1)*HH + h0);
        v2_c = *(const f32x2*)(vecf + ((size_t)src_n*3+2)*HH + h0);
        dc0_c = d_ij[(size_t)e_n*3+0];
        dc1_c = d_ij[(size_t)e_n*3+1];
        dc2_c = d_ij[(size_t)e_n*3+2];
      }
      int el = wid*16 + i;
      int dst = __shfl(dreg, i);
      if (dst != rdst){
        if (rdst >= 0){
          atomicAdd(&vacc[((size_t)rdst*3+0)*HH + h0],     vc00);
          atomicAdd(&vacc[((size_t)rdst*3+0)*HH + h0 + 1], vc01);
          atomicAdd(&vacc[((size_t)rdst*3+1)*HH + h0],     vc10);
          atomicAdd(&vacc[((size_t)rdst*3+1)*HH + h0 + 1], vc11);
          atomicAdd(&vacc[((size_t)rdst*3+2)*HH + h0],     vc20);
          atomicAdd(&vacc[((size_t)rdst*3+2)*HH + h0 + 1], vc21);
        }
        rdst = dst;
        vc00=vc01=vc10=vc11=vc20=vc21=0.f;
      }
      int bs1 = el*512 + h0*2;
      u32 s1 = *(const u32a*)(g2b + SW9(bs1));
      u32 s2 = *(const u32a*)(g2b + SW9(bs1 + 256));
      vc00 += vv0[0]*blo(s1) + blo(s2)*dc0;  vc01 += vv0[1]*bhi(s1) + bhi(s2)*dc0;
      vc10 += vv1[0]*blo(s1) + blo(s2)*dc1;  vc11 += vv1[1]*bhi(s1) + bhi(s2)*dc1;
      vc20 += vv2[0]*blo(s1) + blo(s2)*dc2;  vc21 += vv2[1]*bhi(s1) + bhi(s2)*dc2;
    }
    if (rdst >= 0){
      atomicAdd(&vacc[((size_t)rdst*3+0)*HH + h0],     vc00);
      atomicAdd(&vacc[((size_t)rdst*3+0)*HH + h0 + 1], vc01);
      atomicAdd(&vacc[((size_t)rdst*3+1)*HH + h0],     vc10);
      atomicAdd(&vacc[((size_t)rdst*3+1)*HH + h0 + 1], vc11);
      atomicAdd(&vacc[((size_t)rdst*3+2)*HH + h0],     vc20);
      atomicAdd(&vacc[((size_t)rdst*3+2)*HH + h0 + 1], vc21);
    }
  }
}

// ---------------- update (64-row blocks, LDS-staged xacc) ----------------
__global__ __launch_bounds__(256) void k_upd64(const float* __restrict__ xacc,
    const u16* __restrict__ pb, const u16* __restrict__ v12, const u16* __restrict__ vec3,
    const float* __restrict__ vacc,
    float* __restrict__ dx, float* __restrict__ dvec){
  __shared__ u16 At[64*128];
  char* ab_ = (char*)At;
  int tid = threadIdx.x, wid = tid>>6, lane = tid & 63;
  int r0 = blockIdx.x*64;
#pragma unroll
  for (int pass=0; pass<8; ++pass){
    int idx = pass*1024 + tid*4;
    int row = idx >> 7, col = idx & 127;
    f32x4 v = *(const f32x4*)(xacc + (size_t)(r0+row)*HH + col);
    u32x2 o; o[0]=pk(v[0],v[1]); o[1]=pk(v[2],v[3]);
    ldsw64(ab_, row*256 + col*2, o);
  }
  __syncthreads();
  for (int ct = wid; ct < 8; ct += 4){
    int c0 = ct*16;
    const u16* pw = pb + O_Wo + (size_t)(c0 + (lane&15))*HH + ((lane>>4)<<3);
    short8 w10 = *(const short8a*)(pw);
    short8 w11 = *(const short8a*)(pw + 32);
    short8 w12 = *(const short8a*)(pw + 64);
    short8 w13 = *(const short8a*)(pw + 96);
    short8 w20 = *(const short8a*)(pw + 128*HH);
    short8 w21 = *(const short8a*)(pw + 128*HH + 32);
    short8 w22 = *(const short8a*)(pw + 128*HH + 64);
    short8 w23 = *(const short8a*)(pw + 128*HH + 96);
    short8 w30 = *(const short8a*)(pw + 256*HH);
    short8 w31 = *(const short8a*)(pw + 256*HH + 32);
    short8 w32 = *(const short8a*)(pw + 256*HH + 64);
    short8 w33 = *(const short8a*)(pw + 256*HH + 96);
    int h = c0 + (lane & 15);
    float bo1 = b2f(pb[O_bo + h]), bo2 = b2f(pb[O_bo + 128 + h]), bo3 = b2f(pb[O_bo + 256 + h]);
#pragma unroll
    for (int rg=0; rg<4; ++rg){
      int abse = (rg*16 + (lane&15))*256 + ((lane>>4)<<4);
      short8 af0 = ldsr128(ab_, abse);
      short8 af1 = ldsr128(ab_, abse + 64);
      short8 af2 = ldsr128(ab_, abse + 128);
      short8 af3 = ldsr128(ab_, abse + 192);
      f32x4 a1 = {0,0,0,0}, a2 = {0,0,0,0}, a3 = {0,0,0,0};
      a1 = __builtin_amdgcn_mfma_f32_16x16x32_bf16(af0, w10, a1, 0,0,0);
      a1 = __builtin_amdgcn_mfma_f32_16x16x32_bf16(af1, w11, a1, 0,0,0);
      a1 = __builtin_amdgcn_mfma_f32_16x16x32_bf16(af2, w12, a1, 0,0,0);
      a1 = __builtin_amdgcn_mfma_f32_16x16x32_bf16(af3, w13, a1, 0,0,0);
      a2 = __builtin_amdgcn_mfma_f32_16x16x32_bf16(af0, w20, a2, 0,0,0);
      a2 = __builtin_amdgcn_mfma_f32_16x16x32_bf16(af1, w21, a2, 0,0,0);
      a2 = __builtin_amdgcn_mfma_f32_16x16x32_bf16(af2, w22, a2, 0,0,0);
      a2 = __builtin_amdgcn_mfma_f32_16x16x32_bf16(af3, w23, a2, 0,0,0);
      a3 = __builtin_amdgcn_mfma_f32_16x16x32_bf16(af0, w30, a3, 0,0,0);
      a3 = __builtin_amdgcn_mfma_f32_16x16x32_bf16(af1, w31, a3, 0,0,0);
      a3 = __builtin_amdgcn_mfma_f32_16x16x32_bf16(af2, w32, a3, 0,0,0);
      a3 = __builtin_amdgcn_mfma_f32_16x16x32_bf16(af3, w33, a3, 0,0,0);
#pragma unroll
      for (int j=0;j<4;++j){
        int r = r0 + rg*16 + ((lane>>4)<<2) + j;
        float o1 = a1[j]+bo1, o2 = a2[j]+bo2, o3 = a3[j]+bo3;
        float vdot = 0.f;
#pragma unroll
        for (int c=0;c<3;++c){
          const u16* row = v12 + ((size_t)r*3 + c)*256;
          vdot += b2f(row[h]) * b2f(row[128 + h]);
        }
        dx[(size_t)r*HH + h] = vdot*o2 + o3;
#pragma unroll
        for (int c=0;c<3;++c){
          size_t idx = ((size_t)r*3+c)*HH + h;
          dvec[idx] = b2f(vec3[idx])*o1 + vacc[idx];
        }
      }
    }
  }
}

extern "C" void kernel_launch(void* const* d_in, const int* in_sizes, int n_in,
                              void* d_out, int out_size, void* d_ws, size_t ws_size,
                              hipStream_t stream){
  (void)in_sizes; (void)n_in; (void)out_size; (void)ws_size;
  const float* x     = (const float*)d_in[0];
  const float* vecf  = (const float*)d_in[1];
  const int*   ei    = (const int*)d_in[2];
  const float* r_ij  = (const float*)d_in[3];
  const float* f_ij  = (const float*)d_in[4];
  const float* d_ij  = (const float*)d_in[5];
  const float* aggf  = (const float*)d_in[28];

  char* ws = (char*)d_ws;
  u16*   wsu   = (u16*)d_ws;
  float* xacc  = (float*)(ws + 0);          // [N,128] f32
  float* vacc  = (float*)(ws + 8388608);    // [3N,128] f32
  u16*   Ybuf  = (u16*)(ws + 33554432);     // [3N,256] bf16
  u16*   xn    = (u16*)(ws + 58720256);     // [N,128] bf16
  u16*   vec3  = (u16*)(ws + 67108864);     // [3N,128] bf16
  u16*   qkv   = (u16*)(ws + 79691776);     // [N,384] bf16
  u16*   v12   = (u16*)(ws + 92274688);     // [3N,256] bf16
  int*   cnt   = (int*)(ws + CNT_OFF);
  int*   cur   = (int*)(ws + CUR_OFF);
  int*   se    = (int*)(ws + SE_OFF);

  float* out  = (float*)d_out;
  float* dx   = out;
  float* dvec = out + (size_t)NN*128;
  float* df   = out + (size_t)NN*512;

  Pack p; int c = 0;
  auto add = [&](int idx, unsigned off, unsigned n){ p.d[c].s=(const float*)d_in[idx]; p.d[c].off=off; p.d[c].n=n; ++c; };
  add(8,  O_Wq,   16384); add(10, O_Wk,   16384); add(12, O_Wv,   16384);
  add(14, O_Wdk,  16384); add(16, O_Wdv,  16384); add(23, O_Wf,   16384);
  add(25, O_Wwsrc,16384); add(26, O_Wwtrg,16384);
  add(18, O_Wvec, 49152); add(19, O_Ws,   32768); add(21, O_Wo,   49152);
  add(27, O_Wagg,  8192);
  add(9,  O_bq, 128); add(11, O_bk, 128); add(13, O_bv, 128); add(15, O_bdk, 128);
  add(17, O_bdv, 128); add(20, O_bs, 256); add(22, O_bo, 384); add(24, O_bf, 128);
  add(6,  O_lng, 128); add(7,  O_lnb, 128); add(28, O_agg, 1);
  p.cnt = c;

  hipMemsetAsync(ws, 0, 33554432, stream);              // zero xacc+vacc
  hipMemsetAsync(ws + CNT_OFF, 0, 65536, stream);       // zero cnt
  k_hist<<<dim3(NE/256), 256, 0, stream>>>(ei, cnt);
  k_scan<<<dim3(1), 1024, 0, stream>>>(cnt, cur);
  k_place<<<dim3(NE/256), 256, 0, stream>>>(ei, cur, se);
  k_cvt<<<dim3(128), 256, 0, stream>>>(p, wsu);
  k_ln<<<dim3(NN/4), 256, 0, stream>>>(x, wsu, xn);
  k_qkv64<<<dim3(NN/64), 256, 0, stream>>>(xn, wsu, qkv);
  k_vec64<<<dim3(3*NN/64), 256, 0, stream>>>(vecf, wsu, v12, vec3, Ybuf);
  k_edge<<<dim3(NE/64), 256, 0, stream>>>(f_ij, wsu, qkv, Ybuf, ei, se, r_ij, d_ij,
                                          vecf, aggf, df, xacc, vacc);
  k_upd64<<<dim3(NN/64), 256, 0, stream>>>(xacc, wsu, v12, vec3, vacc, dx, dvec);
}

// Round 16
// 394.922 us; speedup vs baseline: 1.1789x; 1.0253x over previous
//
#include <hip/hip_runtime.h>

#define NN 16384
#define NE 131072
#define HH 128

typedef unsigned short u16;
typedef unsigned int u32;
typedef __attribute__((ext_vector_type(8))) short short8;
typedef __attribute__((ext_vector_type(4))) float f32x4;
typedef __attribute__((ext_vector_type(2))) float f32x2;
typedef __attribute__((ext_vector_type(2))) u32 u32x2;
typedef u16 __attribute__((may_alias)) u16a;
typedef u32 __attribute__((may_alias)) u32a;
typedef short8 __attribute__((may_alias)) short8a;
typedef u32x2 __attribute__((may_alias)) u32x2a;
typedef f32x4 __attribute__((may_alias)) f32x4a;

__device__ __forceinline__ float b2f(u16 u){ u32 i=((u32)u)<<16; float f; __builtin_memcpy(&f,&i,4); return f; }
__device__ __forceinline__ u16 f2b(float f){ u32 i; __builtin_memcpy(&i,&f,4); u32 r=(i+0x7fffu+((i>>16)&1u))>>16; return (u16)r; }
__device__ __forceinline__ float blo(u32 v){ return b2f((u16)(v&0xffffu)); }
__device__ __forceinline__ float bhi(u32 v){ return b2f((u16)(v>>16)); }
__device__ __forceinline__ u32 pk(float a, float b){ return (u32)f2b(a) | ((u32)f2b(b)<<16); }
__device__ __forceinline__ float siluf(float x){ return x/(1.f+__expf(-x)); }

// LDS XOR swizzles (row width 256B / 512B)
#define SW8(b) ((b) ^ ((((b)>>8)&7)<<4))
#define SW9(b) ((b) ^ ((((b)>>9)&7)<<4))
__device__ __forceinline__ u32 ldsr32(const char* base, int b){ return *(const u32a*)(base + SW8(b)); }
__device__ __forceinline__ void ldsw16(char* base, int b, u16 v){ *(u16a*)(base + SW8(b)) = v; }
__device__ __forceinline__ short8 ldsr128(const char* base, int b){ return *(const short8a*)(base + SW8(b)); }
__device__ __forceinline__ void ldsw64(char* base, int b, u32x2 v){ *(u32x2a*)(base + SW8(b)) = v; }

// ws byte layout:
//   0          : xacc f32 [N,128] (8MB)
//   8388608    : vacc f32 [3N,128] (25MB) -> end 33,554,432
//   33554432   : Y [3N,256] bf16 (25MB)
//   58720256   : xn [N,128] bf16 (4MB)
//   67108864   : vec3 [3N,128] bf16 (12.6MB)
//   79691776   : qkv [N,384] bf16 (12.6MB)
//   92274688   : v12 [3N,256] bf16 (25MB) -> 117,440,512
//   117440512  : params bf16 (~545KB)
//   117985280  : cnt int[16384]; 118050816 cur; 118116352 se int[E] -> 118,640,640
//   118640640  : vecb bf16 [3N,128] (12.6MB) -> 131,223,552 (< 128MiB)
#define PBASE 58720256u   // u16 units = byte 117,440,512
enum : unsigned {
  O_Wq=PBASE+0, O_Wk=PBASE+16384, O_Wv=PBASE+32768, O_Wdk=PBASE+49152,
  O_Wdv=PBASE+65536, O_Wf=PBASE+81920, O_Wwsrc=PBASE+98304, O_Wwtrg=PBASE+114688,
  O_Wvec=PBASE+131072, O_Ws=PBASE+180224, O_Wo=PBASE+212992, O_Wagg=PBASE+262144,
  O_bq=PBASE+270336, O_bk=PBASE+270464, O_bv=PBASE+270592, O_bdk=PBASE+270720,
  O_bdv=PBASE+270848, O_bs=PBASE+270976, O_bo=PBASE+271232, O_bf=PBASE+271616,
  O_lng=PBASE+271744, O_lnb=PBASE+271872, O_agg=PBASE+272000
};
#define CNT_OFF 117985280u
#define CUR_OFF 118050816u
#define SE_OFF  118116352u
#define VECB_OFF 118640640u

struct Seg { const float* s; u32 off; u32 n; };
struct Pack { Seg d[25]; int cnt; };

// ---------------- f32 -> bf16 conversion (params only) ----------------
__global__ __launch_bounds__(256) void k_cvt(Pack p, u16* __restrict__ base){
  int tid = blockIdx.x*blockDim.x + threadIdx.x;
  int stride = gridDim.x*blockDim.x;
  for (int s=0; s<p.cnt; ++s){
    const float* src = p.d[s].s;
    u16* dst = base + p.d[s].off;
    int n = (int)p.d[s].n, n4 = n>>2;
    const f32x4* s4 = (const f32x4*)src;
    for (int i=tid; i<n4; i+=stride){
      f32x4 v = s4[i];
      u32x2 o; o[0] = pk(v[0], v[1]); o[1] = pk(v[2], v[3]);
      *(u32x2a*)(dst + 4*(size_t)i) = o;
    }
    for (int i = n4*4 + tid; i < n; i += stride) dst[i] = f2b(src[i]);
  }
}

// ---------------- edge sort by dst: histogram, scan, place ----------------
__global__ __launch_bounds__(256) void k_hist(const int* __restrict__ ei, int* __restrict__ cnt){
  int e = blockIdx.x*256 + threadIdx.x;
  atomicAdd(&cnt[ei[NE + e]], 1);
}
__global__ __launch_bounds__(1024) void k_scan(const int* __restrict__ cnt, int* __restrict__ cur){
  __shared__ int part[1024];
  int t = threadIdx.x;
  int base = t*16;
  int local[16]; int s = 0;
#pragma unroll
  for (int k=0;k<16;++k){ local[k] = cnt[base+k]; s += local[k]; }
  part[t] = s;
  __syncthreads();
  for (int d=1; d<1024; d<<=1){
    int v = (t>=d) ? part[t-d] : 0;
    __syncthreads();
    part[t] += v;
    __syncthreads();
  }
  int run = (t>0) ? part[t-1] : 0;
#pragma unroll
  for (int k=0;k<16;++k){ cur[base+k] = run; run += local[k]; }
}
__global__ __launch_bounds__(256) void k_place(const int* __restrict__ ei, int* __restrict__ cur,
                                               int* __restrict__ se){
  int e = blockIdx.x*256 + threadIdx.x;
  int p = atomicAdd(&cur[ei[NE + e]], 1);
  se[p] = e;
}

// ---------------- LayerNorm (f32 in -> bf16 out) ----------------
__global__ __launch_bounds__(256) void k_ln(const float* __restrict__ x, const u16* __restrict__ pb,
                                            u16* __restrict__ xn){
  int wid = threadIdx.x>>6, lane = threadIdx.x & 63;
  int n = blockIdx.x*4 + wid;
  f32x2 v = *(const f32x2*)(x + (size_t)n*HH + 2*lane);
  float a0 = v[0], a1 = v[1];
  float s = a0 + a1;
#pragma unroll
  for (int m=32; m; m>>=1) s += __shfl_xor(s, m);
  float mu = s*(1.f/128.f);
  float d0 = a0-mu, d1 = a1-mu;
  float vs = d0*d0 + d1*d1;
#pragma unroll
  for (int m=32; m; m>>=1) vs += __shfl_xor(vs, m);
  float rs = rsqrtf(vs*(1.f/128.f) + 1e-5f);
  u32 gg = *(const u32a*)(pb + O_lng + 2*lane);
  u32 bb = *(const u32a*)(pb + O_lnb + 2*lane);
  *(u32a*)(xn + (size_t)n*HH + 2*lane) = pk(d0*rs*blo(gg)+blo(bb), d1*rs*bhi(gg)+bhi(bb));
}

// ---------------- qkv (64-row blocks, LDS-staged A, wave-per-coltile) ----------------
__global__ __launch_bounds__(256) void k_qkv64(const u16* __restrict__ xn,
    const u16* __restrict__ pb, u16* __restrict__ qkv){
  __shared__ u16 At[64*128];
  char* ab_ = (char*)At;
  int tid = threadIdx.x, wid = tid>>6, lane = tid & 63;
  int r0 = blockIdx.x*64;
#pragma unroll
  for (int pass=0; pass<4; ++pass){
    int idx = (pass*256 + tid)*8;            // u16 index, 8 u16 = 16B per iter
    int row = idx >> 7, col = idx & 127;
    f32x4 v = *(const f32x4a*)(xn + (size_t)(r0+row)*HH + col);   // 16B raw copy
    *(f32x4a*)(ab_ + SW8(row*256 + col*2)) = v;
  }
  __syncthreads();
  for (int ct = wid; ct < 24; ct += 4){
    unsigned wo, bo_;
    if (ct < 8)      { wo = O_Wq; bo_ = O_bq; }
    else if (ct <16) { wo = O_Wk; bo_ = O_bk; }
    else             { wo = O_Wv; bo_ = O_bv; }
    int c0 = (ct & 7)*16;
    const u16* pw = pb + wo + (size_t)(c0 + (lane&15))*HH + ((lane>>4)<<3);
    short8 w0 = *(const short8a*)(pw);
    short8 w1 = *(const short8a*)(pw + 32);
    short8 w2 = *(const short8a*)(pw + 64);
    short8 w3 = *(const short8a*)(pw + 96);
    float bb = b2f(pb[bo_ + c0 + (lane&15)]);
    int col = ct*16 + (lane & 15);
#pragma unroll
    for (int rg=0; rg<4; ++rg){
      int abse = (rg*16 + (lane&15))*256 + ((lane>>4)<<4);
      f32x4 acc = {0,0,0,0};
      acc = __builtin_amdgcn_mfma_f32_16x16x32_bf16(ldsr128(ab_, abse),       w0, acc, 0,0,0);
      acc = __builtin_amdgcn_mfma_f32_16x16x32_bf16(ldsr128(ab_, abse + 64),  w1, acc, 0,0,0);
      acc = __builtin_amdgcn_mfma_f32_16x16x32_bf16(ldsr128(ab_, abse + 128), w2, acc, 0,0,0);
      acc = __builtin_amdgcn_mfma_f32_16x16x32_bf16(ldsr128(ab_, abse + 192), w3, acc, 0,0,0);
#pragma unroll
      for (int j=0;j<4;++j){
        int r = r0 + rg*16 + ((lane>>4)<<2) + j;
        qkv[(size_t)r*384 + col] = f2b(acc[j] + bb);
      }
    }
  }
}

// ---------------- vec GEMMs (64-row blocks, LDS-staged f32->bf16 A; also emits vecb) ----------------
__global__ __launch_bounds__(256) void k_vec64(const float* __restrict__ vecf,
    const u16* __restrict__ pb,
    u16* __restrict__ v12, u16* __restrict__ vec3, u16* __restrict__ Y,
    u16* __restrict__ vecb){
  __shared__ u16 At[64*128];
  char* ab_ = (char*)At;
  int tid = threadIdx.x, wid = tid>>6, lane = tid & 63;
  int r0 = blockIdx.x*64;               // rows in [3N]
#pragma unroll
  for (int pass=0; pass<8; ++pass){
    int idx = pass*1024 + tid*4;         // f32 index
    int row = idx >> 7, col = idx & 127;
    f32x4 v = *(const f32x4*)(vecf + (size_t)(r0+row)*HH + col);
    u32x2 o; o[0]=pk(v[0],v[1]); o[1]=pk(v[2],v[3]);
    ldsw64(ab_, row*256 + col*2, o);
    *(u32x2a*)(vecb + (size_t)(r0+row)*HH + col) = o;   // bf16 copy of vec
  }
  __syncthreads();
  for (int ct = wid; ct < 40; ct += 4){
    unsigned wo; int wc0;
    if (ct < 24)      { wo = O_Wvec;  wc0 = ct*16; }
    else if (ct < 32) { wo = O_Wwsrc; wc0 = (ct-24)*16; }
    else              { wo = O_Wwtrg; wc0 = (ct-32)*16; }
    const u16* pw = pb + wo + (size_t)(wc0 + (lane&15))*HH + ((lane>>4)<<3);
    short8 w0 = *(const short8a*)(pw);
    short8 w1 = *(const short8a*)(pw + 32);
    short8 w2 = *(const short8a*)(pw + 64);
    short8 w3 = *(const short8a*)(pw + 96);
    u16* dst; int ldc, dc0;
    if (ct < 16)      { dst = v12;  ldc = 256; dc0 = ct*16; }
    else if (ct < 24) { dst = vec3; ldc = 128; dc0 = (ct-16)*16; }
    else if (ct < 32) { dst = Y;    ldc = 256; dc0 = (ct-24)*16; }
    else              { dst = Y;    ldc = 256; dc0 = (ct-32)*16 + 128; }
    int col = dc0 + (lane & 15);
#pragma unroll
    for (int rg=0; rg<4; ++rg){
      int abse = (rg*16 + (lane&15))*256 + ((lane>>4)<<4);
      f32x4 acc = {0,0,0,0};
      acc = __builtin_amdgcn_mfma_f32_16x16x32_bf16(ldsr128(ab_, abse),       w0, acc, 0,0,0);
      acc = __builtin_amdgcn_mfma_f32_16x16x32_bf16(ldsr128(ab_, abse + 64),  w1, acc, 0,0,0);
      acc = __builtin_amdgcn_mfma_f32_16x16x32_bf16(ldsr128(ab_, abse + 128), w2, acc, 0,0,0);
      acc = __builtin_amdgcn_mfma_f32_16x16x32_bf16(ldsr128(ab_, abse + 192), w3, acc, 0,0,0);
#pragma unroll
      for (int j=0;j<4;++j){
        int r = r0 + rg*16 + ((lane>>4)<<2) + j;
        dst[(size_t)r*ldc + col] = f2b(acc[j]);
      }
    }
  }
}

// ---------------- FUSED edge kernel (round-11 core + XCD-chunked blockIdx + bf16 vec gather) ----------------
__global__ __launch_bounds__(256) void k_edge(const float* __restrict__ f_ij,
    const u16* __restrict__ pb,
    const u16* __restrict__ qkv, const u16* __restrict__ Y,
    const int* __restrict__ ei, const int* __restrict__ se,
    const float* __restrict__ r_ij, const float* __restrict__ d_ij,
    const u16* __restrict__ vecb, const float* __restrict__ aggf,
    float* __restrict__ df, float* __restrict__ xacc, float* __restrict__ vacc){
  __shared__ u16 fs[64*128];
  __shared__ u16 g2s[64*256];
  char* fsb  = (char*)fs;
  char* g2b  = (char*)g2s;
  int tid = threadIdx.x, wid = tid>>6, lane = tid & 63;
  // XCD-aware chunked swizzle: 2048 blocks, 8 XCDs, 256 contiguous tiles per XCD
  int bid = (int)blockIdx.x;
  int t0 = ((bid & 7)*256 + (bid >> 3))*64;
  int ereg=0, dreg=0, sreg=0;
  if (lane < 16){
    ereg = se[t0 + wid*16 + lane];
    dreg = ei[NE + ereg];
    sreg = ei[ereg];
  }
#pragma unroll
  for (int pass=0; pass<8; ++pass){
    int idx = pass*256 + lane*4;
    int rloc = idx >> 7, col = idx & 127;
    int er = __shfl(ereg, rloc);
    f32x4 v = *(const f32x4*)(f_ij + (size_t)er*HH + col);
    u32x2 o; o[0]=pk(v[0],v[1]); o[1]=pk(v[2],v[3]);
    int b = (wid*16 + rloc)*256 + col*2;
    *(u32x2a*)(fsb + SW8(b)) = o;
  }
  {
    int arow = wid*16 + (lane&15);
    int ab = arow*256 + ((lane>>4)<<4);
    short8 a0 = *(const short8a*)(fsb + SW8(ab));
    short8 a1 = *(const short8a*)(fsb + SW8(ab + 64));
    short8 a2 = *(const short8a*)(fsb + SW8(ab + 128));
    short8 a3 = *(const short8a*)(fsb + SW8(ab + 192));
    for (int ct=0; ct<16; ++ct){
      unsigned wo  = (ct<8) ? O_Wdk : O_Wdv;
      unsigned bo_ = (ct<8) ? O_bdk : O_bdv;
      int c0 = (ct&7)*16;
      const u16* pw = pb + wo + (size_t)(c0 + (lane&15))*HH + ((lane>>4)<<3);
      f32x4 acc = {0,0,0,0};
      acc = __builtin_amdgcn_mfma_f32_16x16x32_bf16(a0, *(const short8a*)(pw),      acc, 0,0,0);
      acc = __builtin_amdgcn_mfma_f32_16x16x32_bf16(a1, *(const short8a*)(pw + 32), acc, 0,0,0);
      acc = __builtin_amdgcn_mfma_f32_16x16x32_bf16(a2, *(const short8a*)(pw + 64), acc, 0,0,0);
      acc = __builtin_amdgcn_mfma_f32_16x16x32_bf16(a3, *(const short8a*)(pw + 96), acc, 0,0,0);
      float bb = b2f(pb[bo_ + c0 + (lane&15)]);
#pragma unroll
      for (int j=0;j<4;++j){
        int r = wid*16 + ((lane>>4)<<2) + j;
        int b = r*512 + (ct*16 + (lane&15))*2;
        *(u16a*)(g2b + SW9(b)) = f2b(siluf(acc[j] + bb));
      }
    }
    f32x4 ffa[8];
#pragma unroll
    for (int cf=0; cf<8; ++cf){
      const u16* pw = pb + O_Wf + (size_t)(cf*16 + (lane&15))*HH + ((lane>>4)<<3);
      f32x4 acc = {0,0,0,0};
      acc = __builtin_amdgcn_mfma_f32_16x16x32_bf16(a0, *(const short8a*)(pw),      acc, 0,0,0);
      acc = __builtin_amdgcn_mfma_f32_16x16x32_bf16(a1, *(const short8a*)(pw + 32), acc, 0,0,0);
      acc = __builtin_amdgcn_mfma_f32_16x16x32_bf16(a2, *(const short8a*)(pw + 64), acc, 0,0,0);
      acc = __builtin_amdgcn_mfma_f32_16x16x32_bf16(a3, *(const short8a*)(pw + 96), acc, 0,0,0);
      ffa[cf] = acc;
    }
#pragma unroll
    for (int cf=0; cf<8; ++cf){
      float bb = b2f(pb[O_bf + cf*16 + (lane&15)]);
#pragma unroll
      for (int j=0;j<4;++j){
        int r = wid*16 + ((lane>>4)<<2) + j;
        int b = r*256 + (cf*16 + (lane&15))*2;
        *(u16a*)(fsb + SW8(b)) = f2b(siluf(ffa[cf][j] + bb));
      }
    }
  }
  int h0 = 2*lane;
  {
    int pdst = -1; u32 qq=0, ya0=0, ya1=0, ya2=0;
    int e_c = __shfl(ereg, 0), src_c = __shfl(sreg, 0);
    u32 kk_c  = *(const u32a*)(qkv + (size_t)src_c*384 + 128 + h0);
    u32 vv_c  = *(const u32a*)(qkv + (size_t)src_c*384 + 256 + h0);
    u32 yb0_c = *(const u32a*)(Y + ((size_t)src_c*3+0)*256 + h0);
    u32 yb1_c = *(const u32a*)(Y + ((size_t)src_c*3+1)*256 + h0);
    u32 yb2_c = *(const u32a*)(Y + ((size_t)src_c*3+2)*256 + h0);
    float r_c   = r_ij[e_c];
    float dc0_c = d_ij[(size_t)e_c*3+0];
    float dc1_c = d_ij[(size_t)e_c*3+1];
    float dc2_c = d_ij[(size_t)e_c*3+2];
    for (int i=0;i<16;++i){
      int e = e_c;
      u32 kk=kk_c, vv=vv_c, yb0=yb0_c, yb1=yb1_c, yb2=yb2_c;
      float r=r_c, dc0=dc0_c, dc1=dc1_c, dc2=dc2_c;
      if (i<15){
        int e_n = __shfl(ereg, i+1), src_n = __shfl(sreg, i+1);
        kk_c  = *(const u32a*)(qkv + (size_t)src_n*384 + 128 + h0);
        vv_c  = *(const u32a*)(qkv + (size_t)src_n*384 + 256 + h0);
        yb0_c = *(const u32a*)(Y + ((size_t)src_n*3+0)*256 + h0);
        yb1_c = *(const u32a*)(Y + ((size_t)src_n*3+1)*256 + h0);
        yb2_c = *(const u32a*)(Y + ((size_t)src_n*3+2)*256 + h0);
        r_c   = r_ij[e_n];
        dc0_c = d_ij[(size_t)e_n*3+0];
        dc1_c = d_ij[(size_t)e_n*3+1];
        dc2_c = d_ij[(size_t)e_n*3+2];
        e_c = e_n;
      }
      int el = wid*16 + i;
      int dst = __shfl(dreg, i);
      if (dst != pdst){
        qq  = *(const u32a*)(qkv + (size_t)dst*384 + h0);
        ya0 = *(const u32a*)(Y + ((size_t)dst*3+0)*256 + 128 + h0);
        ya1 = *(const u32a*)(Y + ((size_t)dst*3+1)*256 + 128 + h0);
        ya2 = *(const u32a*)(Y + ((size_t)dst*3+2)*256 + 128 + h0);
        pdst = dst;
      }
      int bdk = el*512 + h0*2;
      u32 dk = *(const u32a*)(g2b + SW9(bdk));
      u32 dv = *(const u32a*)(g2b + SW9(bdk + 256));
      int bff = el*256 + h0*2;
      u32 ff = *(const u32a*)(fsb + SW8(bff));
      float p = blo(qq)*blo(kk)*blo(dk) + bhi(qq)*bhi(kk)*bhi(dk);
      p += __shfl_xor(p,1); p += __shfl_xor(p,2); p += __shfl_xor(p,4);
      float cut = 0.5f*(__cosf(0.6283185307f*r)+1.f) * (r < 5.f ? 1.f : 0.f);
      float attn = siluf(p)*cut;
      float m0 = blo(vv)*blo(dv)*attn, m1 = bhi(vv)*bhi(dv)*attn;
      float ab0,ab1, ad0,ad1, bd0,bd1, ss;
      ab0 = blo(ya0)*blo(yb0); ab1 = bhi(ya0)*bhi(yb0);
      ad0 = blo(ya0)*dc0;      ad1 = bhi(ya0)*dc0;
      bd0 = blo(yb0)*dc0;      bd1 = bhi(yb0)*dc0;
      ss  = dc0*dc0;
      ab0 += blo(ya1)*blo(yb1); ab1 += bhi(ya1)*bhi(yb1);
      ad0 += blo(ya1)*dc1;      ad1 += bhi(ya1)*dc1;
      bd0 += blo(yb1)*dc1;      bd1 += bhi(yb1)*dc1;
      ss  += dc1*dc1;
      ab0 += blo(ya2)*blo(yb2); ab1 += bhi(ya2)*bhi(yb2);
      ad0 += blo(ya2)*dc2;      ad1 += bhi(ya2)*dc2;
      bd0 += blo(yb2)*dc2;      bd1 += bhi(yb2)*dc2;
      ss  += dc2*dc2;
      float t = 2.f - ss;
      f32x2 dfo; dfo[0] = blo(ff)*(ab0 - ad0*bd0*t); dfo[1] = bhi(ff)*(ab1 - ad1*bd1*t);
      *(f32x2*)(df + (size_t)e*HH + h0) = dfo;
      *(u32a*)(fsb + SW8(bff)) = pk(m0, m1);
    }
  }
  float absA = fabsf(aggf[0]);
#pragma unroll
  for (int rr=0; rr<2; ++rr){
    int rt = wid*2 + rr;
    int el2 = wid*16 + 8*rr + ((lane&15)>>1);
    int pb2 = el2*256 + ((lane&15)&1)*128 + ((lane>>4)<<4);
    short8 b0 = *(const short8a*)(fsb + SW8(pb2));
    short8 b1 = *(const short8a*)(fsb + SW8(pb2 + 64));
    for (int ct=0; ct<8; ++ct){
      const u16* pw = pb + O_Wagg + (size_t)(ct*16 + (lane&15))*64 + ((lane>>4)<<3);
      f32x4 acc = {0,0,0,0};
      acc = __builtin_amdgcn_mfma_f32_16x16x32_bf16(b0, *(const short8a*)(pw),      acc, 0,0,0);
      acc = __builtin_amdgcn_mfma_f32_16x16x32_bf16(b1, *(const short8a*)(pw + 32), acc, 0,0,0);
#pragma unroll
      for (int j=0;j<4;++j){
        int r = rt*16 + ((lane>>4)<<2) + j;
        int b = r*256 + (ct*16 + (lane&15))*2;
        *(u16a*)(g2b + SW8(b)) = f2b(fminf(fmaxf(acc[j],0.f),1.f));
      }
    }
  }
  {
    int rdst = -1; float xc0=0.f, xc1=0.f;
    for (int i=0;i<16;++i){
      int el = wid*16 + i;
      int dst = __shfl(dreg, i);
      if (dst != rdst){
        if (rdst >= 0){
          atomicAdd(&xacc[(size_t)rdst*HH + h0],     xc0);
          atomicAdd(&xacc[(size_t)rdst*HH + h0 + 1], xc1);
        }
        rdst = dst; xc0 = xc1 = 0.f;
      }
      int bm = el*256;
      u32 mm = *(const u32a*)(fsb + SW8(bm + h0*2));
      u32 ml = *(const u32a*)(fsb + SW8(bm + (h0&63)*2));
      u32 mh = *(const u32a*)(fsb + SW8(bm + 128 + (h0&63)*2));
      u32 ex0 = *(const u32a*)(g2b + SW8((2*el)*256 + h0*2));
      u32 ex1 = *(const u32a*)(g2b + SW8((2*el+1)*256 + h0*2));
      xc0 += blo(mm) + absA*(blo(ml)*blo(ex0) + blo(mh)*blo(ex1));
      xc1 += bhi(mm) + absA*(bhi(ml)*bhi(ex0) + bhi(mh)*bhi(ex1));
    }
    if (rdst >= 0){
      atomicAdd(&xacc[(size_t)rdst*HH + h0],     xc0);
      atomicAdd(&xacc[(size_t)rdst*HH + h0 + 1], xc1);
    }
  }
  {
    int arow = wid*16 + (lane&15);
    int ab = arow*256 + ((lane>>4)<<4);
    short8 sa0 = *(const short8a*)(fsb + SW8(ab));
    short8 sa1 = *(const short8a*)(fsb + SW8(ab + 64));
    short8 sa2 = *(const short8a*)(fsb + SW8(ab + 128));
    short8 sa3 = *(const short8a*)(fsb + SW8(ab + 192));
    for (int ct=0; ct<16; ++ct){
      const u16* pw = pb + O_Ws + (size_t)(ct*16 + (lane&15))*HH + ((lane>>4)<<3);
      f32x4 acc = {0,0,0,0};
      acc = __builtin_amdgcn_mfma_f32_16x16x32_bf16(sa0, *(const short8a*)(pw),      acc, 0,0,0);
      acc = __builtin_amdgcn_mfma_f32_16x16x32_bf16(sa1, *(const short8a*)(pw + 32), acc, 0,0,0);
      acc = __builtin_amdgcn_mfma_f32_16x16x32_bf16(sa2, *(const short8a*)(pw + 64), acc, 0,0,0);
      acc = __builtin_amdgcn_mfma_f32_16x16x32_bf16(sa3, *(const short8a*)(pw + 96), acc, 0,0,0);
      float bb = b2f(pb[O_bs + ct*16 + (lane&15)]);
#pragma unroll
      for (int j=0;j<4;++j){
        int r = wid*16 + ((lane>>4)<<2) + j;
        int b = r*512 + (ct*16 + (lane&15))*2;
        *(u16a*)(g2b + SW9(b)) = f2b(siluf(acc[j] + bb));
      }
    }
  }
  {
    int rdst = -1;
    float vc00=0.f,vc01=0.f, vc10=0.f,vc11=0.f, vc20=0.f,vc21=0.f;
    int e_c = __shfl(ereg, 0), src_c = __shfl(sreg, 0);
    u32 v0_c = *(const u32a*)(vecb + ((size_t)src_c*3+0)*HH + h0);
    u32 v1_c = *(const u32a*)(vecb + ((size_t)src_c*3+1)*HH + h0);
    u32 v2_c = *(const u32a*)(vecb + ((size_t)src_c*3+2)*HH + h0);
    float dc0_c = d_ij[(size_t)e_c*3+0];
    float dc1_c = d_ij[(size_t)e_c*3+1];
    float dc2_c = d_ij[(size_t)e_c*3+2];
    for (int i=0;i<16;++i){
      u32 vv0=v0_c, vv1=v1_c, vv2=v2_c;
      float dc0=dc0_c, dc1=dc1_c, dc2=dc2_c;
      if (i<15){
        int e_n = __shfl(ereg, i+1), src_n = __shfl(sreg, i+1);
        v0_c = *(const u32a*)(vecb + ((size_t)src_n*3+0)*HH + h0);
        v1_c = *(const u32a*)(vecb + ((size_t)src_n*3+1)*HH + h0);
        v2_c = *(const u32a*)(vecb + ((size_t)src_n*3+2)*HH + h0);
        dc0_c = d_ij[(size_t)e_n*3+0];
        dc1_c = d_ij[(size_t)e_n*3+1];
        dc2_c = d_ij[(size_t)e_n*3+2];
      }
      int el = wid*16 + i;
      int dst = __shfl(dreg, i);
      if (dst != rdst){
        if (rdst >= 0){
          atomicAdd(&vacc[((size_t)rdst*3+0)*HH + h0],     vc00);
          atomicAdd(&vacc[((size_t)rdst*3+0)*HH + h0 + 1], vc01);
          atomicAdd(&vacc[((size_t)rdst*3+1)*HH + h0],     vc10);
          atomicAdd(&vacc[((size_t)rdst*3+1)*HH + h0 + 1], vc11);
          atomicAdd(&vacc[((size_t)rdst*3+2)*HH + h0],     vc20);
          atomicAdd(&vacc[((size_t)rdst*3+2)*HH + h0 + 1], vc21);
        }
        rdst = dst;
        vc00=vc01=vc10=vc11=vc20=vc21=0.f;
      }
      int bs1 = el*512 + h0*2;
      u32 s1 = *(const u32a*)(g2b + SW9(bs1));
      u32 s2 = *(const u32a*)(g2b + SW9(bs1 + 256));
      vc00 += blo(vv0)*blo(s1) + blo(s2)*dc0;  vc01 += bhi(vv0)*bhi(s1) + bhi(s2)*dc0;
      vc10 += blo(vv1)*blo(s1) + blo(s2)*dc1;  vc11 += bhi(vv1)*bhi(s1) + bhi(s2)*dc1;
      vc20 += blo(vv2)*blo(s1) + blo(s2)*dc2;  vc21 += bhi(vv2)*bhi(s1) + bhi(s2)*dc2;
    }
    if (rdst >= 0){
      atomicAdd(&vacc[((size_t)rdst*3+0)*HH + h0],     vc00);
      atomicAdd(&vacc[((size_t)rdst*3+0)*HH + h0 + 1], vc01);
      atomicAdd(&vacc[((size_t)rdst*3+1)*HH + h0],     vc10);
      atomicAdd(&vacc[((size_t)rdst*3+1)*HH + h0 + 1], vc11);
      atomicAdd(&vacc[((size_t)rdst*3+2)*HH + h0],     vc20);
      atomicAdd(&vacc[((size_t)rdst*3+2)*HH + h0 + 1], vc21);
    }
  }
}

// ---------------- update (64-row blocks, LDS-staged xacc) ----------------
__global__ __launch_bounds__(256) void k_upd64(const float* __restrict__ xacc,
    const u16* __restrict__ pb, const u16* __restrict__ v12, const u16* __restrict__ vec3,
    const float* __restrict__ vacc,
    float* __restrict__ dx, float* __restrict__ dvec){
  __shared__ u16 At[64*128];
  char* ab_ = (char*)At;
  int tid = threadIdx.x, wid = tid>>6, lane = tid & 63;
  int r0 = blockIdx.x*64;
#pragma unroll
  for (int pass=0; pass<8; ++pass){
    int idx = pass*1024 + tid*4;
    int row = idx >> 7, col = idx & 127;
    f32x4 v = *(const f32x4*)(xacc + (size_t)(r0+row)*HH + col);
    u32x2 o; o[0]=pk(v[0],v[1]); o[1]=pk(v[2],v[3]);
    ldsw64(ab_, row*256 + col*2, o);
  }
  __syncthreads();
  for (int ct = wid; ct < 8; ct += 4){
    int c0 = ct*16;
    const u16* pw = pb + O_Wo + (size_t)(c0 + (lane&15))*HH + ((lane>>4)<<3);
    short8 w10 = *(const short8a*)(pw);
    short8 w11 = *(const short8a*)(pw + 32);
    short8 w12 = *(const short8a*)(pw + 64);
    short8 w13 = *(const short8a*)(pw + 96);
    short8 w20 = *(const short8a*)(pw + 128*HH);
    short8 w21 = *(const short8a*)(pw + 128*HH + 32);
    short8 w22 = *(const short8a*)(pw + 128*HH + 64);
    short8 w23 = *(const short8a*)(pw + 128*HH + 96);
    short8 w30 = *(const short8a*)(pw + 256*HH);
    short8 w31 = *(const short8a*)(pw + 256*HH + 32);
    short8 w32 = *(const short8a*)(pw + 256*HH + 64);
    short8 w33 = *(const short8a*)(pw + 256*HH + 96);
    int h = c0 + (lane & 15);
    float bo1 = b2f(pb[O_bo + h]), bo2 = b2f(pb[O_bo + 128 + h]), bo3 = b2f(pb[O_bo + 256 + h]);
#pragma unroll
    for (int rg=0; rg<4; ++rg){
      int abse = (rg*16 + (lane&15))*256 + ((lane>>4)<<4);
      short8 af0 = ldsr128(ab_, abse);
      short8 af1 = ldsr128(ab_, abse + 64);
      short8 af2 = ldsr128(ab_, abse + 128);
      short8 af3 = ldsr128(ab_, abse + 192);
      f32x4 a1 = {0,0,0,0}, a2 = {0,0,0,0}, a3 = {0,0,0,0};
      a1 = __builtin_amdgcn_mfma_f32_16x16x32_bf16(af0, w10, a1, 0,0,0);
      a1 = __builtin_amdgcn_mfma_f32_16x16x32_bf16(af1, w11, a1, 0,0,0);
      a1 = __builtin_amdgcn_mfma_f32_16x16x32_bf16(af2, w12, a1, 0,0,0);
      a1 = __builtin_amdgcn_mfma_f32_16x16x32_bf16(af3, w13, a1, 0,0,0);
      a2 = __builtin_amdgcn_mfma_f32_16x16x32_bf16(af0, w20, a2, 0,0,0);
      a2 = __builtin_amdgcn_mfma_f32_16x16x32_bf16(af1, w21, a2, 0,0,0);
      a2 = __builtin_amdgcn_mfma_f32_16x16x32_bf16(af2, w22, a2, 0,0,0);
      a2 = __builtin_amdgcn_mfma_f32_16x16x32_bf16(af3, w23, a2, 0,0,0);
      a3 = __builtin_amdgcn_mfma_f32_16x16x32_bf16(af0, w30, a3, 0,0,0);
      a3 = __builtin_amdgcn_mfma_f32_16x16x32_bf16(af1, w31, a3, 0,0,0);
      a3 = __builtin_amdgcn_mfma_f32_16x16x32_bf16(af2, w32, a3, 0,0,0);
      a3 = __builtin_amdgcn_mfma_f32_16x16x32_bf16(af3, w33, a3, 0,0,0);
#pragma unroll
      for (int j=0;j<4;++j){
        int r = r0 + rg*16 + ((lane>>4)<<2) + j;
        float o1 = a1[j]+bo1, o2 = a2[j]+bo2, o3 = a3[j]+bo3;
        float vdot = 0.f;
#pragma unroll
        for (int c=0;c<3;++c){
          const u16* row = v12 + ((size_t)r*3 + c)*256;
          vdot += b2f(row[h]) * b2f(row[128 + h]);
        }
        dx[(size_t)r*HH + h] = vdot*o2 + o3;
#pragma unroll
        for (int c=0;c<3;++c){
          size_t idx = ((size_t)r*3+c)*HH + h;
          dvec[idx] = b2f(vec3[idx])*o1 + vacc[idx];
        }
      }
    }
  }
}

extern "C" void kernel_launch(void* const* d_in, const int* in_sizes, int n_in,
                              void* d_out, int out_size, void* d_ws, size_t ws_size,
                              hipStream_t stream){
  (void)in_sizes; (void)n_in; (void)out_size; (void)ws_size;
  const float* x     = (const float*)d_in[0];
  const float* vecf  = (const float*)d_in[1];
  const int*   ei    = (const int*)d_in[2];
  const float* r_ij  = (const float*)d_in[3];
  const float* f_ij  = (const float*)d_in[4];
  const float* d_ij  = (const float*)d_in[5];
  const float* aggf  = (const float*)d_in[28];

  char* ws = (char*)d_ws;
  u16*   wsu   = (u16*)d_ws;
  float* xacc  = (float*)(ws + 0);          // [N,128] f32
  float* vacc  = (float*)(ws + 8388608);    // [3N,128] f32
  u16*   Ybuf  = (u16*)(ws + 33554432);     // [3N,256] bf16
  u16*   xn    = (u16*)(ws + 58720256);     // [N,128] bf16
  u16*   vec3  = (u16*)(ws + 67108864);     // [3N,128] bf16
  u16*   qkv   = (u16*)(ws + 79691776);     // [N,384] bf16
  u16*   v12   = (u16*)(ws + 92274688);     // [3N,256] bf16
  int*   cnt   = (int*)(ws + CNT_OFF);
  int*   cur   = (int*)(ws + CUR_OFF);
  int*   se    = (int*)(ws + SE_OFF);
  u16*   vecb  = (u16*)(ws + VECB_OFF);     // [3N,128] bf16

  float* out  = (float*)d_out;
  float* dx   = out;
  float* dvec = out + (size_t)NN*128;
  float* df   = out + (size_t)NN*512;

  Pack p; int c = 0;
  auto add = [&](int idx, unsigned off, unsigned n){ p.d[c].s=(const float*)d_in[idx]; p.d[c].off=off; p.d[c].n=n; ++c; };
  add(8,  O_Wq,   16384); add(10, O_Wk,   16384); add(12, O_Wv,   16384);
  add(14, O_Wdk,  16384); add(16, O_Wdv,  16384); add(23, O_Wf,   16384);
  add(25, O_Wwsrc,16384); add(26, O_Wwtrg,16384);
  add(18, O_Wvec, 49152); add(19, O_Ws,   32768); add(21, O_Wo,   49152);
  add(27, O_Wagg,  8192);
  add(9,  O_bq, 128); add(11, O_bk, 128); add(13, O_bv, 128); add(15, O_bdk, 128);
  add(17, O_bdv, 128); add(20, O_bs, 256); add(22, O_bo, 384); add(24, O_bf, 128);
  add(6,  O_lng, 128); add(7,  O_lnb, 128); add(28, O_agg, 1);
  p.cnt = c;

  hipMemsetAsync(ws, 0, 33554432, stream);              // zero xacc+vacc
  hipMemsetAsync(ws + CNT_OFF, 0, 65536, stream);       // zero cnt
  k_hist<<<dim3(NE/256), 256, 0, stream>>>(ei, cnt);
  k_scan<<<dim3(1), 1024, 0, stream>>>(cnt, cur);
  k_place<<<dim3(NE/256), 256, 0, stream>>>(ei, cur, se);
  k_cvt<<<dim3(128), 256, 0, stream>>>(p, wsu);
  k_ln<<<dim3(NN/4), 256, 0, stream>>>(x, wsu, xn);
  k_qkv64<<<dim3(NN/64), 256, 0, stream>>>(xn, wsu, qkv);
  k_vec64<<<dim3(3*NN/64), 256, 0, stream>>>(vecf, wsu, v12, vec3, Ybuf, vecb);
  k_edge<<<dim3(NE/64), 256, 0, stream>>>(f_ij, wsu, qkv, Ybuf, ei, se, r_ij, d_ij,
                                          vecb, aggf, df, xacc, vacc);
  k_upd64<<<dim3(NN/64), 256, 0, stream>>>(xacc, wsu, v12, vec3, vacc, dx, dvec);
}